// Round 8
// baseline (789.814 us; speedup 1.0000x reference)
//
#include <hip/hip_runtime.h>
#include <hip/hip_bf16.h>

typedef __hip_bfloat16 bf16;
typedef __attribute__((ext_vector_type(8))) short short8;
typedef __attribute__((ext_vector_type(4))) short short4b;
typedef __attribute__((ext_vector_type(4))) float floatx4;

#define DM   768
#define NH   12
#define DH   64
#define DFF  3072
#define TS   4096
#define NB   2
#define MTOK (NB * TS)
#define EPS  1e-5f
#define NEG  -30000.0f

__device__ __forceinline__ float b2f(bf16 v)  { return __bfloat162float(v); }
__device__ __forceinline__ bf16  f2b(float v) { return __float2bfloat16(v); }
__device__ __forceinline__ short sbf(float x) { bf16 b = __float2bfloat16(x); return *(short*)&b; }
__device__ __forceinline__ float ldf(const float* p) { return *p; }
__device__ __forceinline__ float ldf(const bf16*  p) { return b2f(*p); }
__device__ __forceinline__ void stf(float* p, float v) { *p = v; }
__device__ __forceinline__ void stf(bf16*  p, float v) { *p = f2b(v); }

struct TagT { static constexpr bool v = true;  };
struct TagF { static constexpr bool v = false; };

// async global->LDS DMA, 16B per lane.
__device__ __forceinline__ void gl2lds(const bf16* g, short* l) {
    __builtin_amdgcn_global_load_lds(
        (const __attribute__((address_space(1))) void*)g,
        (__attribute__((address_space(3))) void*)l, 16, 0, 0);
}

// ---------------------------------------------------------------------------
// MFMA GEMM with global_load_lds staging (round 4, kept).
// ---------------------------------------------------------------------------
template <int RELU>
__global__ __launch_bounds__(256)
void gemm_lds(const bf16* __restrict__ A, int lda, const bf16* __restrict__ Wt,
              const float* __restrict__ bias, bf16* __restrict__ C, int ldc,
              int N, int K)
{
    __shared__ __align__(16) short As[128 * 32];
    __shared__ __align__(16) short Bs[128 * 32];

    const int tid  = threadIdx.x;
    const int wave = tid >> 6, lane = tid & 63;
    const int wx = wave & 1, wy = wave >> 1;
    const int quad = lane >> 4, fn = lane & 15;
    const int bm = blockIdx.y * 128, bn = blockIdx.x * 128;
    const int l4 = lane >> 2, l8 = (lane & 3) * 8;

    const bf16* gA0 = A  + (size_t)(bm + wave * 16       + l4) * lda + l8;
    const bf16* gA1 = A  + (size_t)(bm + (wave + 4) * 16 + l4) * lda + l8;
    const bf16* gB0 = Wt + (size_t)(bn + wave * 16       + l4) * K   + l8;
    const bf16* gB1 = Wt + (size_t)(bn + (wave + 4) * 16 + l4) * K   + l8;
    short* lA0 = &As[wave * 512];
    short* lA1 = &As[(wave + 4) * 512];
    short* lB0 = &Bs[wave * 512];
    short* lB1 = &Bs[(wave + 4) * 512];

    floatx4 acc[4][4] = {};

    for (int kk = 0; kk < K; kk += 32) {
        __syncthreads();
        gl2lds(gA0 + kk, lA0);
        gl2lds(gA1 + kk, lA1);
        gl2lds(gB0 + kk, lB0);
        gl2lds(gB1 + kk, lB1);
        __syncthreads();

        short8 af[4], bfr[4];
        #pragma unroll
        for (int i = 0; i < 4; ++i) {
            af[i]  = *(const short8*)&As[(wy * 64 + i * 16 + fn) * 32 + quad * 8];
            bfr[i] = *(const short8*)&Bs[(wx * 64 + i * 16 + fn) * 32 + quad * 8];
        }
        #pragma unroll
        for (int i = 0; i < 4; ++i)
            #pragma unroll
            for (int j = 0; j < 4; ++j)
                acc[i][j] = __builtin_amdgcn_mfma_f32_16x16x32_bf16(
                    af[i], bfr[j], acc[i][j], 0, 0, 0);
    }

    #pragma unroll
    for (int j = 0; j < 4; ++j) {
        const int n = bn + wx * 64 + j * 16 + fn;
        const float bv = bias[n];
        #pragma unroll
        for (int i = 0; i < 4; ++i) {
            #pragma unroll
            for (int rg = 0; rg < 4; ++rg) {
                const int m = bm + wy * 64 + i * 16 + quad * 4 + rg;
                float v = acc[i][j][rg] + bv;
                if (RELU) v = fmaxf(v, 0.f);
                C[(size_t)m * ldc + n] = f2b(v);
            }
        }
    }
}

// x (fp32) -> bf16, vectorized 8/thread.
__global__ __launch_bounds__(256)
void xcvt(const float* __restrict__ x, bf16* __restrict__ xb)
{
    const size_t i = ((size_t)blockIdx.x * 256 + threadIdx.x) * 8;
    const float4 a = *(const float4*)&x[i];
    const float4 b = *(const float4*)&x[i + 4];
    short8 v;
    v[0]=sbf(a.x); v[1]=sbf(a.y); v[2]=sbf(a.z); v[3]=sbf(a.w);
    v[4]=sbf(b.x); v[5]=sbf(b.y); v[6]=sbf(b.z); v[7]=sbf(b.w);
    *(short8*)&xb[i] = v;
}

// ---------------------------------------------------------------------------
// MFMA flash attention v8 = v7 (QBLK=128, KVBLK=64, shared K/V staging and
// fragments) with Ss/Ps ALIASED between the two q-subtiles.
//   Rationale (round-7 post-mortem): v7's duplicated Ss/Ps pushed LDS to
//   72.7KB -> 2 blocks/CU -> occupancy 9.7% and a regression. Within a wave,
//   DS instructions execute in order, so the sequence
//     write SsB -> read svB -> write SsA -> read svA   (same buffer)
//   is race-free without barriers (and the compiler cannot reorder accesses
//   to the same array). Same for Ps. LDS: 72.7KB -> 46.1KB -> 3 blocks/CU.
//   Keeps v7's wins: per-key staging traffic halved, K/V fragment reads
//   shared by both subtiles, compile-time causal specialization.
// ---------------------------------------------------------------------------
__global__ __launch_bounds__(256)
void attn_v8(const bf16* __restrict__ QKV, bf16* __restrict__ Out)
{
    __shared__ __align__(16) short Ks[64 * 72];      // [key][d]
    __shared__ __align__(16) short Vt[64 * 72];      // [d][key]
    __shared__ __align__(16) float Ss[4][16 * 68];   // per-wave S scratch (A/B aliased)
    __shared__ __align__(16) short Ps[4][16 * 72];   // per-wave P scratch (A/B aliased)
    __shared__ float Al[2][4][16];
    __shared__ float Ll[2][4][16];

    const int tid  = threadIdx.x;
    const int wave = tid >> 6, lane = tid & 63;
    const int quad = lane >> 4, fn = lane & 15;
    const int bh = blockIdx.y;
    const int b = bh / NH, h = bh % NH;
    const int q0 = (gridDim.x - 1 - blockIdx.x) * 128;
    const int nt = q0 / 64 + 2;              // keys up to q0+127

    const int orow = lane >> 2;              // owned q-row within subtile
    const int okey = (lane & 3) * 16;        // 16-key slice base

    const short* QKVs = (const short*)QKV;

    const size_t rowQA = (size_t)(b * TS + q0 + wave * 16 + fn) * 2304 + h * 64;
    const size_t rowQB = rowQA + (size_t)64 * 2304;
    const short8 qaA0 = *(const short8*)&QKV[rowQA + quad * 8];
    const short8 qaA1 = *(const short8*)&QKV[rowQA + 32 + quad * 8];
    const short8 qaB0 = *(const short8*)&QKV[rowQB + quad * 8];
    const short8 qaB1 = *(const short8*)&QKV[rowQB + 32 + quad * 8];

    float mrA = NEG, lrA = 0.f, mrB = NEG, lrB = 0.f;
    floatx4 oA[4] = {}, oB[4] = {};

    const int sk = tid >> 3, sc8 = (tid & 7) * 8;
    const int vd = tid & 63, vk4 = (tid >> 6) * 4;
    const size_t gK = (size_t)(b * TS) * 2304 + 768  + h * 64 + (size_t)sk * 2304 + sc8;
    const size_t gV = (size_t)(b * TS) * 2304 + 1536 + h * 64 + vd;

    // prologue: tile 0 in registers (bit copies — NaN fix preserved)
    short8 kr0 = *(const short8*)&QKVs[gK];
    short8 kr1 = *(const short8*)&QKVs[gK + (size_t)32 * 2304];
    short4b vr0, vr1, vr2, vr3;
    #pragma unroll
    for (int j = 0; j < 4; ++j) {
        vr0[j] = QKVs[gV + (size_t)(vk4 + j) * 2304];
        vr1[j] = QKVs[gV + (size_t)(16 + vk4 + j) * 2304];
        vr2[j] = QKVs[gV + (size_t)(32 + vk4 + j) * 2304];
        vr3[j] = QKVs[gV + (size_t)(48 + vk4 + j) * 2304];
    }

    for (int t = 0; t < nt; ++t) {
        const int kk0 = t * 64;
        __syncthreads();                 // all reads of tile t-1 done
        *(short8*)&Ks[sk * 72 + sc8]        = kr0;
        *(short8*)&Ks[(sk + 32) * 72 + sc8] = kr1;
        *(short4b*)&Vt[vd * 72 + vk4]       = vr0;
        *(short4b*)&Vt[vd * 72 + 16 + vk4]  = vr1;
        *(short4b*)&Vt[vd * 72 + 32 + vk4]  = vr2;
        *(short4b*)&Vt[vd * 72 + 48 + vk4]  = vr3;
        if (t + 1 < nt) {                // T14 issue-early
            const size_t nk = (size_t)(kk0 + 64) * 2304;
            kr0 = *(const short8*)&QKVs[gK + nk];
            kr1 = *(const short8*)&QKVs[gK + nk + (size_t)32 * 2304];
            #pragma unroll
            for (int j = 0; j < 4; ++j) {
                vr0[j] = QKVs[gV + nk + (size_t)(vk4 + j) * 2304];
                vr1[j] = QKVs[gV + nk + (size_t)(16 + vk4 + j) * 2304];
                vr2[j] = QKVs[gV + nk + (size_t)(32 + vk4 + j) * 2304];
                vr3[j] = QKVs[gV + nk + (size_t)(48 + vk4 + j) * 2304];
            }
        }
        __syncthreads();                 // tile t staged

        // K fragments — shared by subtiles A and B
        short8 ka[4], kb[4];
        #pragma unroll
        for (int ks = 0; ks < 4; ++ks) {
            ka[ks] = *(const short8*)&Ks[(ks * 16 + fn) * 72 + quad * 8];
            kb[ks] = *(const short8*)&Ks[(ks * 16 + fn) * 72 + 32 + quad * 8];
        }

        // ACT: subtile A active; ADIAG: A on its diagonal tile.
        // B is interior iff ACT, diagonal on the last tile.
        auto tile = [&](auto actT, auto adiagT) {
            constexpr bool ACT   = decltype(actT)::v;
            constexpr bool ADIAG = decltype(adiagT)::v;

            // ---- QK^T (both subtiles; independent MFMA chains) ----
            __builtin_amdgcn_s_setprio(1);
            floatx4 sB[4] = {};
            #pragma unroll
            for (int ks = 0; ks < 4; ++ks) {
                sB[ks] = __builtin_amdgcn_mfma_f32_16x16x32_bf16(qaB0, ka[ks], sB[ks], 0, 0, 0);
                sB[ks] = __builtin_amdgcn_mfma_f32_16x16x32_bf16(qaB1, kb[ks], sB[ks], 0, 0, 0);
            }
            floatx4 sA[4] = {};
            if constexpr (ACT) {
                #pragma unroll
                for (int ks = 0; ks < 4; ++ks) {
                    sA[ks] = __builtin_amdgcn_mfma_f32_16x16x32_bf16(qaA0, ka[ks], sA[ks], 0, 0, 0);
                    sA[ks] = __builtin_amdgcn_mfma_f32_16x16x32_bf16(qaA1, kb[ks], sA[ks], 0, 0, 0);
                }
            }
            __builtin_amdgcn_s_setprio(0);

            // ---- B: scale+mask -> Ss, read sv (aliased buffer pass 1) ----
            if constexpr (ACT) {         // B interior
                #pragma unroll
                for (int ks = 0; ks < 4; ++ks)
                    #pragma unroll
                    for (int rg = 0; rg < 4; ++rg)
                        Ss[wave][(quad * 4 + rg) * 68 + ks * 16 + fn] = sB[ks][rg] * 0.125f;
            } else {                     // B diagonal
                const int qgB = q0 + 64 + wave * 16 + quad * 4;
                #pragma unroll
                for (int ks = 0; ks < 4; ++ks)
                    #pragma unroll
                    for (int rg = 0; rg < 4; ++rg) {
                        const float v = (kk0 + ks * 16 + fn <= qgB + rg)
                                            ? sB[ks][rg] * 0.125f : NEG;
                        Ss[wave][(quad * 4 + rg) * 68 + ks * 16 + fn] = v;
                    }
            }
            float svB[16];
            *(float4*)&svB[0]  = *(const float4*)&Ss[wave][orow * 68 + okey];
            *(float4*)&svB[4]  = *(const float4*)&Ss[wave][orow * 68 + okey + 4];
            *(float4*)&svB[8]  = *(const float4*)&Ss[wave][orow * 68 + okey + 8];
            *(float4*)&svB[12] = *(const float4*)&Ss[wave][orow * 68 + okey + 12];

            // ---- A: scale+mask -> Ss (pass 2; DS in-order => svB reads
            //      complete before these writes land), read sv ----
            float svA[16];
            if constexpr (ACT) {
                if constexpr (ADIAG) {
                    const int qgA = q0 + wave * 16 + quad * 4;
                    #pragma unroll
                    for (int ks = 0; ks < 4; ++ks)
                        #pragma unroll
                        for (int rg = 0; rg < 4; ++rg) {
                            const float v = (kk0 + ks * 16 + fn <= qgA + rg)
                                                ? sA[ks][rg] * 0.125f : NEG;
                            Ss[wave][(quad * 4 + rg) * 68 + ks * 16 + fn] = v;
                        }
                } else {
                    #pragma unroll
                    for (int ks = 0; ks < 4; ++ks)
                        #pragma unroll
                        for (int rg = 0; rg < 4; ++rg)
                            Ss[wave][(quad * 4 + rg) * 68 + ks * 16 + fn] = sA[ks][rg] * 0.125f;
                }
                *(float4*)&svA[0]  = *(const float4*)&Ss[wave][orow * 68 + okey];
                *(float4*)&svA[4]  = *(const float4*)&Ss[wave][orow * 68 + okey + 4];
                *(float4*)&svA[8]  = *(const float4*)&Ss[wave][orow * 68 + okey + 8];
                *(float4*)&svA[12] = *(const float4*)&Ss[wave][orow * 68 + okey + 12];
            }

            // ---- softmax B -> Ps pass 1, read pf ----
            {
                float mx = svB[0];
                #pragma unroll
                for (int j = 1; j < 16; ++j) mx = fmaxf(mx, svB[j]);
                mx = fmaxf(mx, __shfl_xor(mx, 1, 64));
                mx = fmaxf(mx, __shfl_xor(mx, 2, 64));
                const float mn2 = fmaxf(mrB, mx);
                float ps = 0.f;
                short8 pb0, pb1;
                #pragma unroll
                for (int j = 0; j < 8; ++j) {
                    const float p = __expf(fminf(svB[j] - mn2, 0.f));
                    ps += p; pb0[j] = sbf(p);
                }
                #pragma unroll
                for (int j = 0; j < 8; ++j) {
                    const float p = __expf(fminf(svB[8 + j] - mn2, 0.f));
                    ps += p; pb1[j] = sbf(p);
                }
                ps += __shfl_xor(ps, 1, 64);
                ps += __shfl_xor(ps, 2, 64);
                const float cr = __expf(fminf(mrB - mn2, 0.f));
                lrB = lrB * cr + ps;
                mrB = mn2;
                *(short8*)&Ps[wave][orow * 72 + okey]     = pb0;
                *(short8*)&Ps[wave][orow * 72 + okey + 8] = pb1;
                if ((lane & 3) == 0) { Al[1][wave][orow] = cr; Ll[1][wave][orow] = lrB; }
            }
            const short8 pfB0 = *(const short8*)&Ps[wave][fn * 72 + quad * 8];
            const short8 pfB1 = *(const short8*)&Ps[wave][fn * 72 + 32 + quad * 8];
            float alB[4];
            #pragma unroll
            for (int rg = 0; rg < 4; ++rg) alB[rg] = Al[1][wave][quad * 4 + rg];

            // ---- softmax A -> Ps pass 2 (after pfB reads, in-order), read pf ----
            short8 pfA0, pfA1;
            float alA[4];
            if constexpr (ACT) {
                float mx = svA[0];
                #pragma unroll
                for (int j = 1; j < 16; ++j) mx = fmaxf(mx, svA[j]);
                mx = fmaxf(mx, __shfl_xor(mx, 1, 64));
                mx = fmaxf(mx, __shfl_xor(mx, 2, 64));
                const float mn2 = fmaxf(mrA, mx);
                float ps = 0.f;
                short8 pb0, pb1;
                #pragma unroll
                for (int j = 0; j < 8; ++j) {
                    const float p = __expf(fminf(svA[j] - mn2, 0.f));
                    ps += p; pb0[j] = sbf(p);
                }
                #pragma unroll
                for (int j = 0; j < 8; ++j) {
                    const float p = __expf(fminf(svA[8 + j] - mn2, 0.f));
                    ps += p; pb1[j] = sbf(p);
                }
                ps += __shfl_xor(ps, 1, 64);
                ps += __shfl_xor(ps, 2, 64);
                const float cr = __expf(fminf(mrA - mn2, 0.f));
                lrA = lrA * cr + ps;
                mrA = mn2;
                *(short8*)&Ps[wave][orow * 72 + okey]     = pb0;
                *(short8*)&Ps[wave][orow * 72 + okey + 8] = pb1;
                if ((lane & 3) == 0) { Al[0][wave][orow] = cr; Ll[0][wave][orow] = lrA; }
                pfA0 = *(const short8*)&Ps[wave][fn * 72 + quad * 8];
                pfA1 = *(const short8*)&Ps[wave][fn * 72 + 32 + quad * 8];
                #pragma unroll
                for (int rg = 0; rg < 4; ++rg) alA[rg] = Al[0][wave][quad * 4 + rg];
            }

            // ---- rescale + PV (V frags shared) ----
            #pragma unroll
            for (int cb = 0; cb < 4; ++cb)
                #pragma unroll
                for (int rg = 0; rg < 4; ++rg) oB[cb][rg] *= alB[rg];
            if constexpr (ACT) {
                #pragma unroll
                for (int cb = 0; cb < 4; ++cb)
                    #pragma unroll
                    for (int rg = 0; rg < 4; ++rg) oA[cb][rg] *= alA[rg];
            }
            __builtin_amdgcn_s_setprio(1);
            #pragma unroll
            for (int cb = 0; cb < 4; ++cb) {
                const short8 vfa = *(const short8*)&Vt[(cb * 16 + fn) * 72 + quad * 8];
                const short8 vfb = *(const short8*)&Vt[(cb * 16 + fn) * 72 + 32 + quad * 8];
                oB[cb] = __builtin_amdgcn_mfma_f32_16x16x32_bf16(pfB0, vfa, oB[cb], 0, 0, 0);
                oB[cb] = __builtin_amdgcn_mfma_f32_16x16x32_bf16(pfB1, vfb, oB[cb], 0, 0, 0);
                if constexpr (ACT) {
                    oA[cb] = __builtin_amdgcn_mfma_f32_16x16x32_bf16(pfA0, vfa, oA[cb], 0, 0, 0);
                    oA[cb] = __builtin_amdgcn_mfma_f32_16x16x32_bf16(pfA1, vfb, oA[cb], 0, 0, 0);
                }
            }
            __builtin_amdgcn_s_setprio(0);
        };

        if (t < nt - 2)       tile(TagT{}, TagF{});   // A interior, B interior
        else if (t == nt - 2) tile(TagT{}, TagT{});   // A diagonal, B interior
        else                  tile(TagF{}, TagF{});   // A off,      B diagonal
    }

    float liA[4], liB[4];
    #pragma unroll
    for (int rg = 0; rg < 4; ++rg) {
        liA[rg] = 1.f / fmaxf(Ll[0][wave][quad * 4 + rg], 1e-20f);
        liB[rg] = 1.f / fmaxf(Ll[1][wave][quad * 4 + rg], 1e-20f);
    }
    #pragma unroll
    for (int cb = 0; cb < 4; ++cb)
        #pragma unroll
        for (int rg = 0; rg < 4; ++rg) {
            const size_t rowA = (size_t)(b * TS + q0 + wave * 16 + quad * 4 + rg);
            Out[rowA * DM + h * 64 + cb * 16 + fn] = f2b(oA[cb][rg] * liA[rg]);
            Out[(rowA + 64) * DM + h * 64 + cb * 16 + fn] = f2b(oB[cb][rg] * liB[rg]);
        }
}

// ---------------------------------------------------------------------------
__global__ __launch_bounds__(256)
void transW(const float* __restrict__ W, bf16* __restrict__ Wt, int K, int N)
{
    __shared__ float t[32][33];
    const int k0 = blockIdx.x * 32, n0 = blockIdx.y * 32;
    const int tx = threadIdx.x, ty = threadIdx.y;
    #pragma unroll
    for (int i = 0; i < 4; ++i)
        t[ty + i * 8][tx] = W[(size_t)(k0 + ty + i * 8) * N + n0 + tx];
    __syncthreads();
    #pragma unroll
    for (int i = 0; i < 4; ++i)
        Wt[(size_t)(n0 + ty + i * 8) * K + k0 + tx] = f2b(t[tx][ty + i * 8]);
}

__global__ __launch_bounds__(256)
void pack_bias(const float* __restrict__ bq, const float* __restrict__ bk,
               const float* __restrict__ bv, float* __restrict__ out)
{
    const int i = blockIdx.x * 256 + threadIdx.x;
    if (i < 3 * DM)
        out[i] = (i < DM) ? bq[i] : (i < 2 * DM) ? bk[i - DM] : bv[i - 2 * DM];
}

template <typename T1, typename T2, typename TOUT>
__global__ __launch_bounds__(256)
void add_ln(const T1* __restrict__ a, const T2* __restrict__ r, int ldr,
            const float* __restrict__ gamma, const float* __restrict__ beta,
            TOUT* __restrict__ out)
{
    const int row = blockIdx.x;
    const size_t offa = (size_t)row * DM;
    const size_t offr = (size_t)row * ldr;
    const int tid = threadIdx.x;

    float v[3];
    float s = 0.f, s2 = 0.f;
    #pragma unroll
    for (int j = 0; j < 3; ++j) {
        const int i = tid + j * 256;
        const float t = ldf(a + offa + i) + ldf(r + offr + i);
        v[j] = t; s += t; s2 += t * t;
    }
    __shared__ float red[256], red2[256];
    red[tid] = s; red2[tid] = s2;
    __syncthreads();
    #pragma unroll
    for (int st = 128; st > 0; st >>= 1) {
        if (tid < st) { red[tid] += red[tid + st]; red2[tid] += red2[tid + st]; }
        __syncthreads();
    }
    const float mu   = red[0] * (1.f / DM);
    const float var  = red2[0] * (1.f / DM) - mu * mu;
    const float rstd = rsqrtf(var + EPS);
    #pragma unroll
    for (int j = 0; j < 3; ++j) {
        const int i = tid + j * 256;
        stf(out + offa + i, (v[j] - mu) * rstd * gamma[i] + beta[i]);
    }
}

// ---------------------------------------------------------------------------
extern "C" void kernel_launch(void* const* d_in, const int* in_sizes, int n_in,
                              void* d_out, int out_size, void* d_ws, size_t ws_size,
                              hipStream_t stream)
{
    (void)in_sizes; (void)n_in; (void)out_size; (void)ws_size;

    const float* x   = (const float*)d_in[0];
    const float* wq  = (const float*)d_in[1];  const float* bq  = (const float*)d_in[2];
    const float* wk  = (const float*)d_in[3];  const float* bk  = (const float*)d_in[4];
    const float* wv  = (const float*)d_in[5];  const float* bv  = (const float*)d_in[6];
    const float* wo  = (const float*)d_in[7];  const float* bo  = (const float*)d_in[8];
    const float* w1  = (const float*)d_in[9];  const float* b1  = (const float*)d_in[10];
    const float* w2  = (const float*)d_in[11]; const float* b2  = (const float*)d_in[12];
    const float* g1  = (const float*)d_in[13]; const float* be1 = (const float*)d_in[14];
    const float* g2  = (const float*)d_in[15]; const float* be2 = (const float*)d_in[16];

    // ws layout (bf16 elems), ~59.8 MB (proven round 6):
    //   QKVb [8192][2304] = 3S | Hb = S | wbuf = 2*DFF*DM | bqkv fp32[2304]
    const size_t S = (size_t)MTOK * DM;
    bf16* QKVb = (bf16*)d_ws;
    bf16* Hb   = QKVb + 3 * S;
    bf16* wbuf = Hb + S;
    float* bqkv = (float*)(wbuf + (size_t)2 * DFF * DM);
    bf16* F1 = QKVb;              // FFN hidden chunk [4096][3072]
    bf16* Yb = QKVb + 2 * S;      // FFN out
    bf16* Pb = QKVb + DM;         // O-proj out -> K-band (dead), ld 2304
    bf16* Ao = Hb;                // attention out (dense; Hb free until LN1)
    bf16* xb = Hb;                // x as bf16 (dead after QKV proj; Hb free)

    const dim3 tblk(32, 8);
    const dim3 blk(256);

    // x -> bf16 (enables global_load_lds staging in the QKV GEMM)
    xcvt<<<dim3(3072), blk, 0, stream>>>(x, xb);

    // QKV projection
    transW<<<dim3(24, 24), tblk, 0, stream>>>(wq, wbuf,                    DM, DM);
    transW<<<dim3(24, 24), tblk, 0, stream>>>(wk, wbuf + (size_t)DM * DM,  DM, DM);
    transW<<<dim3(24, 24), tblk, 0, stream>>>(wv, wbuf + (size_t)2*DM*DM,  DM, DM);
    pack_bias<<<dim3(9), blk, 0, stream>>>(bq, bk, bv, bqkv);
    gemm_lds<0><<<dim3(18, 64), blk, 0, stream>>>(
        xb, DM, wbuf, bqkv, QKVb, 3 * DM, 3 * DM, DM);

    // MFMA flash attention -> Ao (dense 768; overwrites dead xb)
    attn_v8<<<dim3(32, NB * NH), blk, 0, stream>>>(QKVb, Ao);

    // O-projection (Ao -> K-band), LN1 -> Hb (overwrites Ao after read)
    transW<<<dim3(24, 24), tblk, 0, stream>>>(wo, wbuf, DM, DM);
    gemm_lds<0><<<dim3(6, 64), blk, 0, stream>>>(
        Ao, DM, wbuf, bo, Pb, 3 * DM, DM, DM);
    add_ln<float, bf16, bf16><<<dim3(MTOK), blk, 0, stream>>>(
        x, Pb, 3 * DM, g1, be1, Hb);

    // FFN (chunked over M; F1/Yb live in the dead QKVb region)
    transW<<<dim3(24, 96), tblk, 0, stream>>>(w1, wbuf, DM, DFF);
    bf16* w2t = wbuf + (size_t)DFF * DM;
    transW<<<dim3(96, 24), tblk, 0, stream>>>(w2, w2t, DFF, DM);
    for (int m0 = 0; m0 < MTOK; m0 += 4096) {
        gemm_lds<1><<<dim3(24, 32), blk, 0, stream>>>(
            Hb + (size_t)m0 * DM, DM, wbuf, b1, F1, DFF, DFF, DM);
        gemm_lds<0><<<dim3(6, 32), blk, 0, stream>>>(
            F1, DFF, w2t, b2, Yb + (size_t)m0 * DM, DM, DM, DFF);
    }

    add_ln<bf16, bf16, float><<<dim3(MTOK), blk, 0, stream>>>(
        Hb, Yb, DM, g2, be2, (float*)d_out);
}

// Round 9
// 655.836 us; speedup vs baseline: 1.2043x; 1.2043x over previous
//
#include <hip/hip_runtime.h>
#include <hip/hip_bf16.h>

typedef __hip_bfloat16 bf16;
typedef __attribute__((ext_vector_type(8))) short short8;
typedef __attribute__((ext_vector_type(4))) short short4b;
typedef __attribute__((ext_vector_type(4))) float floatx4;

#define DM   768
#define NH   12
#define DH   64
#define DFF  3072
#define TS   4096
#define NB   2
#define MTOK (NB * TS)
#define EPS  1e-5f
#define NEG  -30000.0f

__device__ __forceinline__ float b2f(bf16 v)  { return __bfloat162float(v); }
__device__ __forceinline__ bf16  f2b(float v) { return __float2bfloat16(v); }
__device__ __forceinline__ short sbf(float x) { bf16 b = __float2bfloat16(x); return *(short*)&b; }
__device__ __forceinline__ float ldf(const float* p) { return *p; }
__device__ __forceinline__ float ldf(const bf16*  p) { return b2f(*p); }
__device__ __forceinline__ void stf(float* p, float v) { *p = v; }
__device__ __forceinline__ void stf(bf16*  p, float v) { *p = f2b(v); }

// async global->LDS DMA, 16B per lane.
__device__ __forceinline__ void gl2lds(const bf16* g, short* l) {
    __builtin_amdgcn_global_load_lds(
        (const __attribute__((address_space(1))) void*)g,
        (__attribute__((address_space(3))) void*)l, 16, 0, 0);
}

// ---------------------------------------------------------------------------
// MFMA GEMM, 128x128 tile, global_load_lds staging (round 4, kept for the
// well-gridded GEMMs: QKV proj and FFN1).
// ---------------------------------------------------------------------------
template <int RELU>
__global__ __launch_bounds__(256)
void gemm_lds(const bf16* __restrict__ A, int lda, const bf16* __restrict__ Wt,
              const float* __restrict__ bias, bf16* __restrict__ C, int ldc,
              int N, int K)
{
    __shared__ __align__(16) short As[128 * 32];
    __shared__ __align__(16) short Bs[128 * 32];

    const int tid  = threadIdx.x;
    const int wave = tid >> 6, lane = tid & 63;
    const int wx = wave & 1, wy = wave >> 1;
    const int quad = lane >> 4, fn = lane & 15;
    const int bm = blockIdx.y * 128, bn = blockIdx.x * 128;
    const int l4 = lane >> 2, l8 = (lane & 3) * 8;

    const bf16* gA0 = A  + (size_t)(bm + wave * 16       + l4) * lda + l8;
    const bf16* gA1 = A  + (size_t)(bm + (wave + 4) * 16 + l4) * lda + l8;
    const bf16* gB0 = Wt + (size_t)(bn + wave * 16       + l4) * K   + l8;
    const bf16* gB1 = Wt + (size_t)(bn + (wave + 4) * 16 + l4) * K   + l8;
    short* lA0 = &As[wave * 512];
    short* lA1 = &As[(wave + 4) * 512];
    short* lB0 = &Bs[wave * 512];
    short* lB1 = &Bs[(wave + 4) * 512];

    floatx4 acc[4][4] = {};

    for (int kk = 0; kk < K; kk += 32) {
        __syncthreads();
        gl2lds(gA0 + kk, lA0);
        gl2lds(gA1 + kk, lA1);
        gl2lds(gB0 + kk, lB0);
        gl2lds(gB1 + kk, lB1);
        __syncthreads();

        short8 af[4], bfr[4];
        #pragma unroll
        for (int i = 0; i < 4; ++i) {
            af[i]  = *(const short8*)&As[(wy * 64 + i * 16 + fn) * 32 + quad * 8];
            bfr[i] = *(const short8*)&Bs[(wx * 64 + i * 16 + fn) * 32 + quad * 8];
        }
        #pragma unroll
        for (int i = 0; i < 4; ++i)
            #pragma unroll
            for (int j = 0; j < 4; ++j)
                acc[i][j] = __builtin_amdgcn_mfma_f32_16x16x32_bf16(
                    af[i], bfr[j], acc[i][j], 0, 0, 0);
    }

    #pragma unroll
    for (int j = 0; j < 4; ++j) {
        const int n = bn + wx * 64 + j * 16 + fn;
        const float bv = bias[n];
        #pragma unroll
        for (int i = 0; i < 4; ++i) {
            #pragma unroll
            for (int rg = 0; rg < 4; ++rg) {
                const int m = bm + wy * 64 + i * 16 + quad * 4 + rg;
                float v = acc[i][j][rg] + bv;
                if (RELU) v = fmaxf(v, 0.f);
                C[(size_t)m * ldc + n] = f2b(v);
            }
        }
    }
}

// ---------------------------------------------------------------------------
// MFMA GEMM, 64x64 tile — for grid-starved N=768 GEMMs (FFN2, O-proj).
//   Round-9 theory: FFN2 at 128^2 tiles runs 192 blocks on 256 CUs (0.75/CU,
//   64 CUs idle, K=3072 deep loop, no cross-block TLP). 64^2 tiles give
//   768 blocks/chunk = 3 blocks/CU; co-resident blocks overlap each other's
//   barrier/staging stalls (the TLP mechanism validated in the attn ladder).
//   LDS 8KB. Same staging pattern, same K-order -> bit-identical results.
// ---------------------------------------------------------------------------
template <int RELU>
__global__ __launch_bounds__(256)
void gemm_lds64(const bf16* __restrict__ A, int lda, const bf16* __restrict__ Wt,
                const float* __restrict__ bias, bf16* __restrict__ C, int ldc,
                int N, int K)
{
    __shared__ __align__(16) short As[64 * 32];
    __shared__ __align__(16) short Bs[64 * 32];

    const int tid  = threadIdx.x;
    const int wave = tid >> 6, lane = tid & 63;
    const int wx = wave & 1, wy = wave >> 1;
    const int quad = lane >> 4, fn = lane & 15;
    const int bm = blockIdx.y * 64, bn = blockIdx.x * 64;
    const int l4 = lane >> 2, l8 = (lane & 3) * 8;

    // each wave stages one 16-row chunk of A and one of B
    const bf16* gA = A  + (size_t)(bm + wave * 16 + l4) * lda + l8;
    const bf16* gB = Wt + (size_t)(bn + wave * 16 + l4) * K   + l8;
    short* lA = &As[wave * 512];
    short* lB = &Bs[wave * 512];

    floatx4 acc[2][2] = {};

    for (int kk = 0; kk < K; kk += 32) {
        __syncthreads();
        gl2lds(gA + kk, lA);
        gl2lds(gB + kk, lB);
        __syncthreads();

        short8 af[2], bfr[2];
        #pragma unroll
        for (int i = 0; i < 2; ++i) {
            af[i]  = *(const short8*)&As[(wy * 32 + i * 16 + fn) * 32 + quad * 8];
            bfr[i] = *(const short8*)&Bs[(wx * 32 + i * 16 + fn) * 32 + quad * 8];
        }
        #pragma unroll
        for (int i = 0; i < 2; ++i)
            #pragma unroll
            for (int j = 0; j < 2; ++j)
                acc[i][j] = __builtin_amdgcn_mfma_f32_16x16x32_bf16(
                    af[i], bfr[j], acc[i][j], 0, 0, 0);
    }

    #pragma unroll
    for (int j = 0; j < 2; ++j) {
        const int n = bn + wx * 32 + j * 16 + fn;
        const float bv = bias[n];
        #pragma unroll
        for (int i = 0; i < 2; ++i) {
            #pragma unroll
            for (int rg = 0; rg < 4; ++rg) {
                const int m = bm + wy * 32 + i * 16 + quad * 4 + rg;
                float v = acc[i][j][rg] + bv;
                if (RELU) v = fmaxf(v, 0.f);
                C[(size_t)m * ldc + n] = f2b(v);
            }
        }
    }
}

// x (fp32) -> bf16, vectorized 8/thread.
__global__ __launch_bounds__(256)
void xcvt(const float* __restrict__ x, bf16* __restrict__ xb)
{
    const size_t i = ((size_t)blockIdx.x * 256 + threadIdx.x) * 8;
    const float4 a = *(const float4*)&x[i];
    const float4 b = *(const float4*)&x[i + 4];
    short8 v;
    v[0]=sbf(a.x); v[1]=sbf(a.y); v[2]=sbf(a.z); v[3]=sbf(a.w);
    v[4]=sbf(b.x); v[5]=sbf(b.y); v[6]=sbf(b.z); v[7]=sbf(b.w);
    *(short8*)&xb[i] = v;
}

// ---------------------------------------------------------------------------
// MFMA flash attention v6 (PROVEN round 5, 281 us) — unchanged revert.
// ---------------------------------------------------------------------------
__global__ __launch_bounds__(256)
void attn_v6(const bf16* __restrict__ QKV, bf16* __restrict__ Out)
{
    __shared__ __align__(16) short Ks[64 * 72];      // [key][d]
    __shared__ __align__(16) short Vt[64 * 72];      // [d][key]
    __shared__ __align__(16) float Ss[4][16 * 68];   // per-wave S [q][key] fp32
    __shared__ __align__(16) short Ps[4][16 * 72];   // per-wave P [q][key] bf16
    __shared__ float Al[4][16];                      // per-row alpha
    __shared__ float Ll[4][16];                      // per-row l

    const int tid  = threadIdx.x;
    const int wave = tid >> 6, lane = tid & 63;
    const int quad = lane >> 4, fn = lane & 15;
    const int bh = blockIdx.y;
    const int b = bh / NH, h = bh % NH;
    const int q0 = (gridDim.x - 1 - blockIdx.x) * 64;
    const int nt = q0 / 64 + 1;              // 64-key tiles
    const int qwmin = q0 + wave * 16;

    const int orow = lane >> 2;              // 0..15 (owned q-row)
    const int okey = (lane & 3) * 16;        // 16-key slice base

    const short* QKVs = (const short*)QKV;   // bit view for LDS staging

    const size_t rowQ = (size_t)(b * TS + q0 + wave * 16 + fn) * 2304 + h * 64;
    const short8 qa0 = *(const short8*)&QKV[rowQ + quad * 8];
    const short8 qa1 = *(const short8*)&QKV[rowQ + 32 + quad * 8];

    float mrow = NEG, lrow = 0.f;
    floatx4 o[4] = {};

    const int sk = tid >> 3, sc8 = (tid & 7) * 8;    // K staging: 32 rows/pass
    const int vd = tid & 63, vk4 = (tid >> 6) * 4;   // V staging: 4+4+4+4 keys
    const size_t gK = (size_t)(b * TS) * 2304 + 768  + h * 64 + (size_t)sk * 2304 + sc8;
    const size_t gV = (size_t)(b * TS) * 2304 + 1536 + h * 64 + vd;

    // prologue: load tile 0 into registers (bit copies — NaN fix preserved)
    short8 kr0 = *(const short8*)&QKVs[gK];
    short8 kr1 = *(const short8*)&QKVs[gK + (size_t)32 * 2304];
    short4b vr0, vr1, vr2, vr3;
    #pragma unroll
    for (int j = 0; j < 4; ++j) {
        vr0[j] = QKVs[gV + (size_t)(vk4 + j) * 2304];
        vr1[j] = QKVs[gV + (size_t)(16 + vk4 + j) * 2304];
        vr2[j] = QKVs[gV + (size_t)(32 + vk4 + j) * 2304];
        vr3[j] = QKVs[gV + (size_t)(48 + vk4 + j) * 2304];
    }

    for (int t = 0; t < nt; ++t) {
        const int kk0 = t * 64;
        __syncthreads();                 // all reads of tile t-1 done
        *(short8*)&Ks[sk * 72 + sc8]        = kr0;
        *(short8*)&Ks[(sk + 32) * 72 + sc8] = kr1;
        *(short4b*)&Vt[vd * 72 + vk4]       = vr0;
        *(short4b*)&Vt[vd * 72 + 16 + vk4]  = vr1;
        *(short4b*)&Vt[vd * 72 + 32 + vk4]  = vr2;
        *(short4b*)&Vt[vd * 72 + 48 + vk4]  = vr3;
        if (t + 1 < nt) {                // T14: issue next-tile loads early
            const size_t nk = (size_t)(kk0 + 64) * 2304;
            kr0 = *(const short8*)&QKVs[gK + nk];
            kr1 = *(const short8*)&QKVs[gK + nk + (size_t)32 * 2304];
            #pragma unroll
            for (int j = 0; j < 4; ++j) {
                vr0[j] = QKVs[gV + nk + (size_t)(vk4 + j) * 2304];
                vr1[j] = QKVs[gV + nk + (size_t)(16 + vk4 + j) * 2304];
                vr2[j] = QKVs[gV + nk + (size_t)(32 + vk4 + j) * 2304];
                vr3[j] = QKVs[gV + nk + (size_t)(48 + vk4 + j) * 2304];
            }
        }
        __syncthreads();                 // tile t staged

        if (kk0 > qwmin + 15) continue;  // fully masked for this wave

        // ---- S = Q K^T : 4 sub-tiles of 16 keys, 8 MFMA ----
        __builtin_amdgcn_s_setprio(1);
        floatx4 s[4] = {};
        #pragma unroll
        for (int ks = 0; ks < 4; ++ks) {
            const short8 ka = *(const short8*)&Ks[(ks * 16 + fn) * 72 + quad * 8];
            const short8 kb = *(const short8*)&Ks[(ks * 16 + fn) * 72 + 32 + quad * 8];
            s[ks] = __builtin_amdgcn_mfma_f32_16x16x32_bf16(qa0, ka, s[ks], 0, 0, 0);
            s[ks] = __builtin_amdgcn_mfma_f32_16x16x32_bf16(qa1, kb, s[ks], 0, 0, 0);
        }
        __builtin_amdgcn_s_setprio(0);

        // scale + mask, S -> wave-private LDS (no barrier needed)
        const int qg = q0 + wave * 16 + quad * 4;
        if (kk0 + 63 <= qwmin) {         // interior tile: mask statically true
            #pragma unroll
            for (int ks = 0; ks < 4; ++ks)
                #pragma unroll
                for (int rg = 0; rg < 4; ++rg)
                    Ss[wave][(quad * 4 + rg) * 68 + ks * 16 + fn] = s[ks][rg] * 0.125f;
        } else {
            #pragma unroll
            for (int ks = 0; ks < 4; ++ks)
                #pragma unroll
                for (int rg = 0; rg < 4; ++rg) {
                    const float v = (kk0 + ks * 16 + fn <= qg + rg)
                                        ? s[ks][rg] * 0.125f : NEG;
                    Ss[wave][(quad * 4 + rg) * 68 + ks * 16 + fn] = v;
                }
        }

        // ---- LDS softmax (lane owns row lane>>2, 16-key slice) ----
        float sv[16];
        *(float4*)&sv[0]  = *(const float4*)&Ss[wave][orow * 68 + okey];
        *(float4*)&sv[4]  = *(const float4*)&Ss[wave][orow * 68 + okey + 4];
        *(float4*)&sv[8]  = *(const float4*)&Ss[wave][orow * 68 + okey + 8];
        *(float4*)&sv[12] = *(const float4*)&Ss[wave][orow * 68 + okey + 12];
        float mx = sv[0];
        #pragma unroll
        for (int j = 1; j < 16; ++j) mx = fmaxf(mx, sv[j]);
        mx = fmaxf(mx, __shfl_xor(mx, 1, 64));
        mx = fmaxf(mx, __shfl_xor(mx, 2, 64));
        const float mn2 = fmaxf(mrow, mx);
        float ps = 0.f;
        short8 pb0, pb1;
        #pragma unroll
        for (int j = 0; j < 8; ++j) {
            const float p = __expf(fminf(sv[j] - mn2, 0.f));
            ps += p;
            pb0[j] = sbf(p);
        }
        #pragma unroll
        for (int j = 0; j < 8; ++j) {
            const float p = __expf(fminf(sv[8 + j] - mn2, 0.f));
            ps += p;
            pb1[j] = sbf(p);
        }
        ps += __shfl_xor(ps, 1, 64);
        ps += __shfl_xor(ps, 2, 64);
        const float cr = __expf(fminf(mrow - mn2, 0.f));
        lrow = lrow * cr + ps;
        mrow = mn2;
        *(short8*)&Ps[wave][orow * 72 + okey]     = pb0;
        *(short8*)&Ps[wave][orow * 72 + okey + 8] = pb1;
        if ((lane & 3) == 0) { Al[wave][orow] = cr; Ll[wave][orow] = lrow; }

        // ---- rescale accumulator + PV MFMA (wave-private, no barrier) ----
        float al[4];
        #pragma unroll
        for (int rg = 0; rg < 4; ++rg) al[rg] = Al[wave][quad * 4 + rg];
        #pragma unroll
        for (int cb = 0; cb < 4; ++cb)
            #pragma unroll
            for (int rg = 0; rg < 4; ++rg) o[cb][rg] *= al[rg];
        const short8 pf0 = *(const short8*)&Ps[wave][fn * 72 + quad * 8];
        const short8 pf1 = *(const short8*)&Ps[wave][fn * 72 + 32 + quad * 8];
        __builtin_amdgcn_s_setprio(1);
        #pragma unroll
        for (int cb = 0; cb < 4; ++cb) {
            const short8 vfa = *(const short8*)&Vt[(cb * 16 + fn) * 72 + quad * 8];
            o[cb] = __builtin_amdgcn_mfma_f32_16x16x32_bf16(pf0, vfa, o[cb], 0, 0, 0);
        }
        #pragma unroll
        for (int cb = 0; cb < 4; ++cb) {
            const short8 vfb = *(const short8*)&Vt[(cb * 16 + fn) * 72 + 32 + quad * 8];
            o[cb] = __builtin_amdgcn_mfma_f32_16x16x32_bf16(pf1, vfb, o[cb], 0, 0, 0);
        }
        __builtin_amdgcn_s_setprio(0);
    }

    float li[4];
    #pragma unroll
    for (int rg = 0; rg < 4; ++rg)
        li[rg] = 1.f / fmaxf(Ll[wave][quad * 4 + rg], 1e-20f);
    #pragma unroll
    for (int cb = 0; cb < 4; ++cb)
        #pragma unroll
        for (int rg = 0; rg < 4; ++rg) {
            const size_t row = (size_t)(b * TS + q0 + wave * 16 + quad * 4 + rg);
            Out[row * DM + h * 64 + cb * 16 + fn] = f2b(o[cb][rg] * li[rg]);
        }
}

// ---------------------------------------------------------------------------
__global__ __launch_bounds__(256)
void transW(const float* __restrict__ W, bf16* __restrict__ Wt, int K, int N)
{
    __shared__ float t[32][33];
    const int k0 = blockIdx.x * 32, n0 = blockIdx.y * 32;
    const int tx = threadIdx.x, ty = threadIdx.y;
    #pragma unroll
    for (int i = 0; i < 4; ++i)
        t[ty + i * 8][tx] = W[(size_t)(k0 + ty + i * 8) * N + n0 + tx];
    __syncthreads();
    #pragma unroll
    for (int i = 0; i < 4; ++i)
        Wt[(size_t)(n0 + ty + i * 8) * K + k0 + tx] = f2b(t[tx][ty + i * 8]);
}

__global__ __launch_bounds__(256)
void pack_bias(const float* __restrict__ bq, const float* __restrict__ bk,
               const float* __restrict__ bv, float* __restrict__ out)
{
    const int i = blockIdx.x * 256 + threadIdx.x;
    if (i < 3 * DM)
        out[i] = (i < DM) ? bq[i] : (i < 2 * DM) ? bk[i - DM] : bv[i - 2 * DM];
}

template <typename T1, typename T2, typename TOUT>
__global__ __launch_bounds__(256)
void add_ln(const T1* __restrict__ a, const T2* __restrict__ r, int ldr,
            const float* __restrict__ gamma, const float* __restrict__ beta,
            TOUT* __restrict__ out)
{
    const int row = blockIdx.x;
    const size_t offa = (size_t)row * DM;
    const size_t offr = (size_t)row * ldr;
    const int tid = threadIdx.x;

    float v[3];
    float s = 0.f, s2 = 0.f;
    #pragma unroll
    for (int j = 0; j < 3; ++j) {
        const int i = tid + j * 256;
        const float t = ldf(a + offa + i) + ldf(r + offr + i);
        v[j] = t; s += t; s2 += t * t;
    }
    __shared__ float red[256], red2[256];
    red[tid] = s; red2[tid] = s2;
    __syncthreads();
    #pragma unroll
    for (int st = 128; st > 0; st >>= 1) {
        if (tid < st) { red[tid] += red[tid + st]; red2[tid] += red2[tid + st]; }
        __syncthreads();
    }
    const float mu   = red[0] * (1.f / DM);
    const float var  = red2[0] * (1.f / DM) - mu * mu;
    const float rstd = rsqrtf(var + EPS);
    #pragma unroll
    for (int j = 0; j < 3; ++j) {
        const int i = tid + j * 256;
        stf(out + offa + i, (v[j] - mu) * rstd * gamma[i] + beta[i]);
    }
}

// ---------------------------------------------------------------------------
extern "C" void kernel_launch(void* const* d_in, const int* in_sizes, int n_in,
                              void* d_out, int out_size, void* d_ws, size_t ws_size,
                              hipStream_t stream)
{
    (void)in_sizes; (void)n_in; (void)out_size; (void)ws_size;

    const float* x   = (const float*)d_in[0];
    const float* wq  = (const float*)d_in[1];  const float* bq  = (const float*)d_in[2];
    const float* wk  = (const float*)d_in[3];  const float* bk  = (const float*)d_in[4];
    const float* wv  = (const float*)d_in[5];  const float* bv  = (const float*)d_in[6];
    const float* wo  = (const float*)d_in[7];  const float* bo  = (const float*)d_in[8];
    const float* w1  = (const float*)d_in[9];  const float* b1  = (const float*)d_in[10];
    const float* w2  = (const float*)d_in[11]; const float* b2  = (const float*)d_in[12];
    const float* g1  = (const float*)d_in[13]; const float* be1 = (const float*)d_in[14];
    const float* g2  = (const float*)d_in[15]; const float* be2 = (const float*)d_in[16];

    // ws layout (bf16 elems), ~59.8 MB (proven round 6):
    //   QKVb [8192][2304] = 3S | Hb = S | wbuf = 2*DFF*DM | bqkv fp32[2304]
    const size_t S = (size_t)MTOK * DM;
    bf16* QKVb = (bf16*)d_ws;
    bf16* Hb   = QKVb + 3 * S;
    bf16* wbuf = Hb + S;
    float* bqkv = (float*)(wbuf + (size_t)2 * DFF * DM);
    bf16* F1 = QKVb;              // FFN hidden chunk [4096][3072]
    bf16* Yb = QKVb + 2 * S;      // FFN out
    bf16* Pb = QKVb + DM;         // O-proj out -> K-band (dead), ld 2304
    bf16* Ao = Hb;                // attention out (dense; Hb free until LN1)
    bf16* xb = Hb;                // x as bf16 (dead after QKV proj; Hb free)

    const dim3 tblk(32, 8);
    const dim3 blk(256);

    // x -> bf16 (enables global_load_lds staging in the QKV GEMM)
    xcvt<<<dim3(3072), blk, 0, stream>>>(x, xb);

    // QKV projection (well-gridded: 1152 blocks at 128^2)
    transW<<<dim3(24, 24), tblk, 0, stream>>>(wq, wbuf,                    DM, DM);
    transW<<<dim3(24, 24), tblk, 0, stream>>>(wk, wbuf + (size_t)DM * DM,  DM, DM);
    transW<<<dim3(24, 24), tblk, 0, stream>>>(wv, wbuf + (size_t)2*DM*DM,  DM, DM);
    pack_bias<<<dim3(9), blk, 0, stream>>>(bq, bk, bv, bqkv);
    gemm_lds<0><<<dim3(18, 64), blk, 0, stream>>>(
        xb, DM, wbuf, bqkv, QKVb, 3 * DM, 3 * DM, DM);

    // MFMA flash attention -> Ao (dense 768; overwrites dead xb)
    attn_v6<<<dim3(64, NB * NH), blk, 0, stream>>>(QKVb, Ao);

    // O-projection: 64^2 tiles -> (12,128) = 1536 blocks (was 384)
    transW<<<dim3(24, 24), tblk, 0, stream>>>(wo, wbuf, DM, DM);
    gemm_lds64<0><<<dim3(12, 128), blk, 0, stream>>>(
        Ao, DM, wbuf, bo, Pb, 3 * DM, DM, DM);
    add_ln<float, bf16, bf16><<<dim3(MTOK), blk, 0, stream>>>(
        x, Pb, 3 * DM, g1, be1, Hb);

    // FFN (chunked over M; F1/Yb live in the dead QKVb region)
    transW<<<dim3(24, 96), tblk, 0, stream>>>(w1, wbuf, DM, DFF);
    bf16* w2t = wbuf + (size_t)DFF * DM;
    transW<<<dim3(96, 24), tblk, 0, stream>>>(w2, w2t, DFF, DM);
    for (int m0 = 0; m0 < MTOK; m0 += 4096) {
        gemm_lds<1><<<dim3(24, 32), blk, 0, stream>>>(
            Hb + (size_t)m0 * DM, DM, wbuf, b1, F1, DFF, DFF, DM);
        // FFN2: 64^2 tiles -> (12,64) = 768 blocks = 3/CU (was 192 = 0.75/CU)
        gemm_lds64<0><<<dim3(12, 64), blk, 0, stream>>>(
            F1, DFF, w2t, b2, Yb + (size_t)m0 * DM, DM, DM, DFF);
    }

    add_ln<bf16, bf16, float><<<dim3(MTOK), blk, 0, stream>>>(
        Hb, Yb, DM, g2, be2, (float*)d_out);
}

// Round 10
// 640.888 us; speedup vs baseline: 1.2324x; 1.0233x over previous
//
#include <hip/hip_runtime.h>
#include <hip/hip_bf16.h>

typedef __hip_bfloat16 bf16;
typedef __attribute__((ext_vector_type(8))) short short8;
typedef __attribute__((ext_vector_type(4))) short short4b;
typedef __attribute__((ext_vector_type(4))) float floatx4;

#define DM   768
#define NH   12
#define DH   64
#define DFF  3072
#define TS   4096
#define NB   2
#define MTOK (NB * TS)
#define EPS  1e-5f
#define NEG  -30000.0f

__device__ __forceinline__ float b2f(bf16 v)  { return __bfloat162float(v); }
__device__ __forceinline__ bf16  f2b(float v) { return __float2bfloat16(v); }
__device__ __forceinline__ short sbf(float x) { bf16 b = __float2bfloat16(x); return *(short*)&b; }
__device__ __forceinline__ float ldf(const float* p) { return *p; }
__device__ __forceinline__ float ldf(const bf16*  p) { return b2f(*p); }
__device__ __forceinline__ void stf(float* p, float v) { *p = v; }
__device__ __forceinline__ void stf(bf16*  p, float v) { *p = f2b(v); }

// async global->LDS DMA, 16B per lane.
__device__ __forceinline__ void gl2lds(const bf16* g, short* l) {
    __builtin_amdgcn_global_load_lds(
        (const __attribute__((address_space(1))) void*)g,
        (__attribute__((address_space(3))) void*)l, 16, 0, 0);
}

// ---------------------------------------------------------------------------
// MFMA GEMM, 128x128 tile, BK=64 double-staged (round 10).
//   Round-10 theory: the dominant GEMM stall is the vmcnt(0)+lgkmcnt(0)
//   drain at each __syncthreads (m97 analysis, ~20%). Stage TWO K-sub-tiles
//   per barrier pair (8 DMA issues -> barrier -> 32 MFMA): barrier pairs
//   halve, in-flight DMA doubles. Compute order h=0 then h=1 == old kk,
//   kk+32 order -> bit-identical output. LDS 32.8KB (>=4 blocks/CU; grids
//   here are <=4.5/CU so not binding).
// ---------------------------------------------------------------------------
template <int RELU>
__global__ __launch_bounds__(256)
void gemm_lds(const bf16* __restrict__ A, int lda, const bf16* __restrict__ Wt,
              const float* __restrict__ bias, bf16* __restrict__ C, int ldc,
              int N, int K)
{
    __shared__ __align__(16) short As[2][128 * 32];
    __shared__ __align__(16) short Bs[2][128 * 32];

    const int tid  = threadIdx.x;
    const int wave = tid >> 6, lane = tid & 63;
    const int wx = wave & 1, wy = wave >> 1;
    const int quad = lane >> 4, fn = lane & 15;
    const int bm = blockIdx.y * 128, bn = blockIdx.x * 128;
    const int l4 = lane >> 2, l8 = (lane & 3) * 8;

    const bf16* gA0 = A  + (size_t)(bm + wave * 16       + l4) * lda + l8;
    const bf16* gA1 = A  + (size_t)(bm + (wave + 4) * 16 + l4) * lda + l8;
    const bf16* gB0 = Wt + (size_t)(bn + wave * 16       + l4) * K   + l8;
    const bf16* gB1 = Wt + (size_t)(bn + (wave + 4) * 16 + l4) * K   + l8;
    const int cA0 = wave * 512, cA1 = (wave + 4) * 512;

    floatx4 acc[4][4] = {};

    for (int kk = 0; kk < K; kk += 64) {
        __syncthreads();
        gl2lds(gA0 + kk,      &As[0][cA0]);
        gl2lds(gA1 + kk,      &As[0][cA1]);
        gl2lds(gB0 + kk,      &Bs[0][cA0]);
        gl2lds(gB1 + kk,      &Bs[0][cA1]);
        gl2lds(gA0 + kk + 32, &As[1][cA0]);
        gl2lds(gA1 + kk + 32, &As[1][cA1]);
        gl2lds(gB0 + kk + 32, &Bs[1][cA0]);
        gl2lds(gB1 + kk + 32, &Bs[1][cA1]);
        __syncthreads();

        #pragma unroll
        for (int h = 0; h < 2; ++h) {
            short8 af[4], bfr[4];
            #pragma unroll
            for (int i = 0; i < 4; ++i) {
                af[i]  = *(const short8*)&As[h][(wy * 64 + i * 16 + fn) * 32 + quad * 8];
                bfr[i] = *(const short8*)&Bs[h][(wx * 64 + i * 16 + fn) * 32 + quad * 8];
            }
            #pragma unroll
            for (int i = 0; i < 4; ++i)
                #pragma unroll
                for (int j = 0; j < 4; ++j)
                    acc[i][j] = __builtin_amdgcn_mfma_f32_16x16x32_bf16(
                        af[i], bfr[j], acc[i][j], 0, 0, 0);
        }
    }

    #pragma unroll
    for (int j = 0; j < 4; ++j) {
        const int n = bn + wx * 64 + j * 16 + fn;
        const float bv = bias[n];
        #pragma unroll
        for (int i = 0; i < 4; ++i) {
            #pragma unroll
            for (int rg = 0; rg < 4; ++rg) {
                const int m = bm + wy * 64 + i * 16 + quad * 4 + rg;
                float v = acc[i][j][rg] + bv;
                if (RELU) v = fmaxf(v, 0.f);
                C[(size_t)m * ldc + n] = f2b(v);
            }
        }
    }
}

// ---------------------------------------------------------------------------
// MFMA GEMM, 64x64 tile, BK=64 double-staged — for grid-starved N=768 GEMMs
// (FFN2, O-proj; round 9 +30us, now with halved barriers). LDS 16.4KB.
// ---------------------------------------------------------------------------
template <int RELU>
__global__ __launch_bounds__(256)
void gemm_lds64(const bf16* __restrict__ A, int lda, const bf16* __restrict__ Wt,
                const float* __restrict__ bias, bf16* __restrict__ C, int ldc,
                int N, int K)
{
    __shared__ __align__(16) short As[2][64 * 32];
    __shared__ __align__(16) short Bs[2][64 * 32];

    const int tid  = threadIdx.x;
    const int wave = tid >> 6, lane = tid & 63;
    const int wx = wave & 1, wy = wave >> 1;
    const int quad = lane >> 4, fn = lane & 15;
    const int bm = blockIdx.y * 64, bn = blockIdx.x * 64;
    const int l4 = lane >> 2, l8 = (lane & 3) * 8;

    const bf16* gA = A  + (size_t)(bm + wave * 16 + l4) * lda + l8;
    const bf16* gB = Wt + (size_t)(bn + wave * 16 + l4) * K   + l8;
    const int cw = wave * 512;

    floatx4 acc[2][2] = {};

    for (int kk = 0; kk < K; kk += 64) {
        __syncthreads();
        gl2lds(gA + kk,      &As[0][cw]);
        gl2lds(gB + kk,      &Bs[0][cw]);
        gl2lds(gA + kk + 32, &As[1][cw]);
        gl2lds(gB + kk + 32, &Bs[1][cw]);
        __syncthreads();

        #pragma unroll
        for (int h = 0; h < 2; ++h) {
            short8 af[2], bfr[2];
            #pragma unroll
            for (int i = 0; i < 2; ++i) {
                af[i]  = *(const short8*)&As[h][(wy * 32 + i * 16 + fn) * 32 + quad * 8];
                bfr[i] = *(const short8*)&Bs[h][(wx * 32 + i * 16 + fn) * 32 + quad * 8];
            }
            #pragma unroll
            for (int i = 0; i < 2; ++i)
                #pragma unroll
                for (int j = 0; j < 2; ++j)
                    acc[i][j] = __builtin_amdgcn_mfma_f32_16x16x32_bf16(
                        af[i], bfr[j], acc[i][j], 0, 0, 0);
        }
    }

    #pragma unroll
    for (int j = 0; j < 2; ++j) {
        const int n = bn + wx * 32 + j * 16 + fn;
        const float bv = bias[n];
        #pragma unroll
        for (int i = 0; i < 2; ++i) {
            #pragma unroll
            for (int rg = 0; rg < 4; ++rg) {
                const int m = bm + wy * 32 + i * 16 + quad * 4 + rg;
                float v = acc[i][j][rg] + bv;
                if (RELU) v = fmaxf(v, 0.f);
                C[(size_t)m * ldc + n] = f2b(v);
            }
        }
    }
}

// x (fp32) -> bf16, vectorized 8/thread.
__global__ __launch_bounds__(256)
void xcvt(const float* __restrict__ x, bf16* __restrict__ xb)
{
    const size_t i = ((size_t)blockIdx.x * 256 + threadIdx.x) * 8;
    const float4 a = *(const float4*)&x[i];
    const float4 b = *(const float4*)&x[i + 4];
    short8 v;
    v[0]=sbf(a.x); v[1]=sbf(a.y); v[2]=sbf(a.z); v[3]=sbf(a.w);
    v[4]=sbf(b.x); v[5]=sbf(b.y); v[6]=sbf(b.z); v[7]=sbf(b.w);
    *(short8*)&xb[i] = v;
}

// ---------------------------------------------------------------------------
// MFMA flash attention v6 (PROVEN round 5, ~283 us) — unchanged.
// ---------------------------------------------------------------------------
__global__ __launch_bounds__(256)
void attn_v6(const bf16* __restrict__ QKV, bf16* __restrict__ Out)
{
    __shared__ __align__(16) short Ks[64 * 72];      // [key][d]
    __shared__ __align__(16) short Vt[64 * 72];      // [d][key]
    __shared__ __align__(16) float Ss[4][16 * 68];   // per-wave S [q][key] fp32
    __shared__ __align__(16) short Ps[4][16 * 72];   // per-wave P [q][key] bf16
    __shared__ float Al[4][16];                      // per-row alpha
    __shared__ float Ll[4][16];                      // per-row l

    const int tid  = threadIdx.x;
    const int wave = tid >> 6, lane = tid & 63;
    const int quad = lane >> 4, fn = lane & 15;
    const int bh = blockIdx.y;
    const int b = bh / NH, h = bh % NH;
    const int q0 = (gridDim.x - 1 - blockIdx.x) * 64;
    const int nt = q0 / 64 + 1;              // 64-key tiles
    const int qwmin = q0 + wave * 16;

    const int orow = lane >> 2;              // 0..15 (owned q-row)
    const int okey = (lane & 3) * 16;        // 16-key slice base

    const short* QKVs = (const short*)QKV;   // bit view for LDS staging

    const size_t rowQ = (size_t)(b * TS + q0 + wave * 16 + fn) * 2304 + h * 64;
    const short8 qa0 = *(const short8*)&QKV[rowQ + quad * 8];
    const short8 qa1 = *(const short8*)&QKV[rowQ + 32 + quad * 8];

    float mrow = NEG, lrow = 0.f;
    floatx4 o[4] = {};

    const int sk = tid >> 3, sc8 = (tid & 7) * 8;    // K staging: 32 rows/pass
    const int vd = tid & 63, vk4 = (tid >> 6) * 4;   // V staging: 4+4+4+4 keys
    const size_t gK = (size_t)(b * TS) * 2304 + 768  + h * 64 + (size_t)sk * 2304 + sc8;
    const size_t gV = (size_t)(b * TS) * 2304 + 1536 + h * 64 + vd;

    // prologue: load tile 0 into registers (bit copies — NaN fix preserved)
    short8 kr0 = *(const short8*)&QKVs[gK];
    short8 kr1 = *(const short8*)&QKVs[gK + (size_t)32 * 2304];
    short4b vr0, vr1, vr2, vr3;
    #pragma unroll
    for (int j = 0; j < 4; ++j) {
        vr0[j] = QKVs[gV + (size_t)(vk4 + j) * 2304];
        vr1[j] = QKVs[gV + (size_t)(16 + vk4 + j) * 2304];
        vr2[j] = QKVs[gV + (size_t)(32 + vk4 + j) * 2304];
        vr3[j] = QKVs[gV + (size_t)(48 + vk4 + j) * 2304];
    }

    for (int t = 0; t < nt; ++t) {
        const int kk0 = t * 64;
        __syncthreads();                 // all reads of tile t-1 done
        *(short8*)&Ks[sk * 72 + sc8]        = kr0;
        *(short8*)&Ks[(sk + 32) * 72 + sc8] = kr1;
        *(short4b*)&Vt[vd * 72 + vk4]       = vr0;
        *(short4b*)&Vt[vd * 72 + 16 + vk4]  = vr1;
        *(short4b*)&Vt[vd * 72 + 32 + vk4]  = vr2;
        *(short4b*)&Vt[vd * 72 + 48 + vk4]  = vr3;
        if (t + 1 < nt) {                // T14: issue next-tile loads early
            const size_t nk = (size_t)(kk0 + 64) * 2304;
            kr0 = *(const short8*)&QKVs[gK + nk];
            kr1 = *(const short8*)&QKVs[gK + nk + (size_t)32 * 2304];
            #pragma unroll
            for (int j = 0; j < 4; ++j) {
                vr0[j] = QKVs[gV + nk + (size_t)(vk4 + j) * 2304];
                vr1[j] = QKVs[gV + nk + (size_t)(16 + vk4 + j) * 2304];
                vr2[j] = QKVs[gV + nk + (size_t)(32 + vk4 + j) * 2304];
                vr3[j] = QKVs[gV + nk + (size_t)(48 + vk4 + j) * 2304];
            }
        }
        __syncthreads();                 // tile t staged

        if (kk0 > qwmin + 15) continue;  // fully masked for this wave

        // ---- S = Q K^T : 4 sub-tiles of 16 keys, 8 MFMA ----
        __builtin_amdgcn_s_setprio(1);
        floatx4 s[4] = {};
        #pragma unroll
        for (int ks = 0; ks < 4; ++ks) {
            const short8 ka = *(const short8*)&Ks[(ks * 16 + fn) * 72 + quad * 8];
            const short8 kb = *(const short8*)&Ks[(ks * 16 + fn) * 72 + 32 + quad * 8];
            s[ks] = __builtin_amdgcn_mfma_f32_16x16x32_bf16(qa0, ka, s[ks], 0, 0, 0);
            s[ks] = __builtin_amdgcn_mfma_f32_16x16x32_bf16(qa1, kb, s[ks], 0, 0, 0);
        }
        __builtin_amdgcn_s_setprio(0);

        // scale + mask, S -> wave-private LDS (no barrier needed)
        const int qg = q0 + wave * 16 + quad * 4;
        if (kk0 + 63 <= qwmin) {         // interior tile: mask statically true
            #pragma unroll
            for (int ks = 0; ks < 4; ++ks)
                #pragma unroll
                for (int rg = 0; rg < 4; ++rg)
                    Ss[wave][(quad * 4 + rg) * 68 + ks * 16 + fn] = s[ks][rg] * 0.125f;
        } else {
            #pragma unroll
            for (int ks = 0; ks < 4; ++ks)
                #pragma unroll
                for (int rg = 0; rg < 4; ++rg) {
                    const float v = (kk0 + ks * 16 + fn <= qg + rg)
                                        ? s[ks][rg] * 0.125f : NEG;
                    Ss[wave][(quad * 4 + rg) * 68 + ks * 16 + fn] = v;
                }
        }

        // ---- LDS softmax (lane owns row lane>>2, 16-key slice) ----
        float sv[16];
        *(float4*)&sv[0]  = *(const float4*)&Ss[wave][orow * 68 + okey];
        *(float4*)&sv[4]  = *(const float4*)&Ss[wave][orow * 68 + okey + 4];
        *(float4*)&sv[8]  = *(const float4*)&Ss[wave][orow * 68 + okey + 8];
        *(float4*)&sv[12] = *(const float4*)&Ss[wave][orow * 68 + okey + 12];
        float mx = sv[0];
        #pragma unroll
        for (int j = 1; j < 16; ++j) mx = fmaxf(mx, sv[j]);
        mx = fmaxf(mx, __shfl_xor(mx, 1, 64));
        mx = fmaxf(mx, __shfl_xor(mx, 2, 64));
        const float mn2 = fmaxf(mrow, mx);
        float ps = 0.f;
        short8 pb0, pb1;
        #pragma unroll
        for (int j = 0; j < 8; ++j) {
            const float p = __expf(fminf(sv[j] - mn2, 0.f));
            ps += p;
            pb0[j] = sbf(p);
        }
        #pragma unroll
        for (int j = 0; j < 8; ++j) {
            const float p = __expf(fminf(sv[8 + j] - mn2, 0.f));
            ps += p;
            pb1[j] = sbf(p);
        }
        ps += __shfl_xor(ps, 1, 64);
        ps += __shfl_xor(ps, 2, 64);
        const float cr = __expf(fminf(mrow - mn2, 0.f));
        lrow = lrow * cr + ps;
        mrow = mn2;
        *(short8*)&Ps[wave][orow * 72 + okey]     = pb0;
        *(short8*)&Ps[wave][orow * 72 + okey + 8] = pb1;
        if ((lane & 3) == 0) { Al[wave][orow] = cr; Ll[wave][orow] = lrow; }

        // ---- rescale accumulator + PV MFMA (wave-private, no barrier) ----
        float al[4];
        #pragma unroll
        for (int rg = 0; rg < 4; ++rg) al[rg] = Al[wave][quad * 4 + rg];
        #pragma unroll
        for (int cb = 0; cb < 4; ++cb)
            #pragma unroll
            for (int rg = 0; rg < 4; ++rg) o[cb][rg] *= al[rg];
        const short8 pf0 = *(const short8*)&Ps[wave][fn * 72 + quad * 8];
        const short8 pf1 = *(const short8*)&Ps[wave][fn * 72 + 32 + quad * 8];
        __builtin_amdgcn_s_setprio(1);
        #pragma unroll
        for (int cb = 0; cb < 4; ++cb) {
            const short8 vfa = *(const short8*)&Vt[(cb * 16 + fn) * 72 + quad * 8];
            o[cb] = __builtin_amdgcn_mfma_f32_16x16x32_bf16(pf0, vfa, o[cb], 0, 0, 0);
        }
        #pragma unroll
        for (int cb = 0; cb < 4; ++cb) {
            const short8 vfb = *(const short8*)&Vt[(cb * 16 + fn) * 72 + 32 + quad * 8];
            o[cb] = __builtin_amdgcn_mfma_f32_16x16x32_bf16(pf1, vfb, o[cb], 0, 0, 0);
        }
        __builtin_amdgcn_s_setprio(0);
    }

    float li[4];
    #pragma unroll
    for (int rg = 0; rg < 4; ++rg)
        li[rg] = 1.f / fmaxf(Ll[wave][quad * 4 + rg], 1e-20f);
    #pragma unroll
    for (int cb = 0; cb < 4; ++cb)
        #pragma unroll
        for (int rg = 0; rg < 4; ++rg) {
            const size_t row = (size_t)(b * TS + q0 + wave * 16 + quad * 4 + rg);
            Out[row * DM + h * 64 + cb * 16 + fn] = f2b(o[cb][rg] * li[rg]);
        }
}

// ---------------------------------------------------------------------------
__global__ __launch_bounds__(256)
void transW(const float* __restrict__ W, bf16* __restrict__ Wt, int K, int N)
{
    __shared__ float t[32][33];
    const int k0 = blockIdx.x * 32, n0 = blockIdx.y * 32;
    const int tx = threadIdx.x, ty = threadIdx.y;
    #pragma unroll
    for (int i = 0; i < 4; ++i)
        t[ty + i * 8][tx] = W[(size_t)(k0 + ty + i * 8) * N + n0 + tx];
    __syncthreads();
    #pragma unroll
    for (int i = 0; i < 4; ++i)
        Wt[(size_t)(n0 + ty + i * 8) * K + k0 + tx] = f2b(t[tx][ty + i * 8]);
}

__global__ __launch_bounds__(256)
void pack_bias(const float* __restrict__ bq, const float* __restrict__ bk,
               const float* __restrict__ bv, float* __restrict__ out)
{
    const int i = blockIdx.x * 256 + threadIdx.x;
    if (i < 3 * DM)
        out[i] = (i < DM) ? bq[i] : (i < 2 * DM) ? bk[i - DM] : bv[i - 2 * DM];
}

template <typename T1, typename T2, typename TOUT>
__global__ __launch_bounds__(256)
void add_ln(const T1* __restrict__ a, const T2* __restrict__ r, int ldr,
            const float* __restrict__ gamma, const float* __restrict__ beta,
            TOUT* __restrict__ out)
{
    const int row = blockIdx.x;
    const size_t offa = (size_t)row * DM;
    const size_t offr = (size_t)row * ldr;
    const int tid = threadIdx.x;

    float v[3];
    float s = 0.f, s2 = 0.f;
    #pragma unroll
    for (int j = 0; j < 3; ++j) {
        const int i = tid + j * 256;
        const float t = ldf(a + offa + i) + ldf(r + offr + i);
        v[j] = t; s += t; s2 += t * t;
    }
    __shared__ float red[256], red2[256];
    red[tid] = s; red2[tid] = s2;
    __syncthreads();
    #pragma unroll
    for (int st = 128; st > 0; st >>= 1) {
        if (tid < st) { red[tid] += red[tid + st]; red2[tid] += red2[tid + st]; }
        __syncthreads();
    }
    const float mu   = red[0] * (1.f / DM);
    const float var  = red2[0] * (1.f / DM) - mu * mu;
    const float rstd = rsqrtf(var + EPS);
    #pragma unroll
    for (int j = 0; j < 3; ++j) {
        const int i = tid + j * 256;
        stf(out + offa + i, (v[j] - mu) * rstd * gamma[i] + beta[i]);
    }
}

// ---------------------------------------------------------------------------
extern "C" void kernel_launch(void* const* d_in, const int* in_sizes, int n_in,
                              void* d_out, int out_size, void* d_ws, size_t ws_size,
                              hipStream_t stream)
{
    (void)in_sizes; (void)n_in; (void)out_size; (void)ws_size;

    const float* x   = (const float*)d_in[0];
    const float* wq  = (const float*)d_in[1];  const float* bq  = (const float*)d_in[2];
    const float* wk  = (const float*)d_in[3];  const float* bk  = (const float*)d_in[4];
    const float* wv  = (const float*)d_in[5];  const float* bv  = (const float*)d_in[6];
    const float* wo  = (const float*)d_in[7];  const float* bo  = (const float*)d_in[8];
    const float* w1  = (const float*)d_in[9];  const float* b1  = (const float*)d_in[10];
    const float* w2  = (const float*)d_in[11]; const float* b2  = (const float*)d_in[12];
    const float* g1  = (const float*)d_in[13]; const float* be1 = (const float*)d_in[14];
    const float* g2  = (const float*)d_in[15]; const float* be2 = (const float*)d_in[16];

    // ws layout (bf16 elems), ~59.8 MB (proven round 6):
    //   QKVb [8192][2304] = 3S | Hb = S | wbuf = 2*DFF*DM | bqkv fp32[2304]
    const size_t S = (size_t)MTOK * DM;
    bf16* QKVb = (bf16*)d_ws;
    bf16* Hb   = QKVb + 3 * S;
    bf16* wbuf = Hb + S;
    float* bqkv = (float*)(wbuf + (size_t)2 * DFF * DM);
    bf16* F1 = QKVb;              // FFN hidden chunk [4096][3072]
    bf16* Yb = QKVb + 2 * S;      // FFN out
    bf16* Pb = QKVb + DM;         // O-proj out -> K-band (dead), ld 2304
    bf16* Ao = Hb;                // attention out (dense; Hb free until LN1)
    bf16* xb = Hb;                // x as bf16 (dead after QKV proj; Hb free)

    const dim3 tblk(32, 8);
    const dim3 blk(256);

    // x -> bf16 (enables global_load_lds staging in the QKV GEMM)
    xcvt<<<dim3(3072), blk, 0, stream>>>(x, xb);

    // QKV projection (well-gridded: 1152 blocks at 128^2)
    transW<<<dim3(24, 24), tblk, 0, stream>>>(wq, wbuf,                    DM, DM);
    transW<<<dim3(24, 24), tblk, 0, stream>>>(wk, wbuf + (size_t)DM * DM,  DM, DM);
    transW<<<dim3(24, 24), tblk, 0, stream>>>(wv, wbuf + (size_t)2*DM*DM,  DM, DM);
    pack_bias<<<dim3(9), blk, 0, stream>>>(bq, bk, bv, bqkv);
    gemm_lds<0><<<dim3(18, 64), blk, 0, stream>>>(
        xb, DM, wbuf, bqkv, QKVb, 3 * DM, 3 * DM, DM);

    // MFMA flash attention -> Ao (dense 768; overwrites dead xb)
    attn_v6<<<dim3(64, NB * NH), blk, 0, stream>>>(QKVb, Ao);

    // O-projection: 64^2 tiles -> (12,128) = 1536 blocks
    transW<<<dim3(24, 24), tblk, 0, stream>>>(wo, wbuf, DM, DM);
    gemm_lds64<0><<<dim3(12, 128), blk, 0, stream>>>(
        Ao, DM, wbuf, bo, Pb, 3 * DM, DM, DM);
    add_ln<float, bf16, bf16><<<dim3(MTOK), blk, 0, stream>>>(
        x, Pb, 3 * DM, g1, be1, Hb);

    // FFN (chunked over M; F1/Yb live in the dead QKVb region)
    transW<<<dim3(24, 96), tblk, 0, stream>>>(w1, wbuf, DM, DFF);
    bf16* w2t = wbuf + (size_t)DFF * DM;
    transW<<<dim3(96, 24), tblk, 0, stream>>>(w2, w2t, DFF, DM);
    for (int m0 = 0; m0 < MTOK; m0 += 4096) {
        gemm_lds<1><<<dim3(24, 32), blk, 0, stream>>>(
            Hb + (size_t)m0 * DM, DM, wbuf, b1, F1, DFF, DFF, DM);
        // FFN2: 64^2 tiles -> (12,64) = 768 blocks = 3/CU
        gemm_lds64<0><<<dim3(12, 64), blk, 0, stream>>>(
            F1, DFF, w2t, b2, Yb + (size_t)m0 * DM, DM, DM, DFF);
    }

    add_ln<bf16, bf16, float><<<dim3(MTOK), blk, 0, stream>>>(
        Hb, Yb, DM, g2, be2, (float*)d_out);
}

// Round 11
// 551.589 us; speedup vs baseline: 1.4319x; 1.1619x over previous
//
#include <hip/hip_runtime.h>
#include <hip/hip_bf16.h>

typedef __hip_bfloat16 bf16;
typedef __attribute__((ext_vector_type(8))) short short8;
typedef __attribute__((ext_vector_type(4))) short short4b;
typedef __attribute__((ext_vector_type(4))) float floatx4;

#define DM   768
#define NH   12
#define DH   64
#define DFF  3072
#define TS   4096
#define NB   2
#define MTOK (NB * TS)
#define EPS  1e-5f
#define NEG  -30000.0f

__device__ __forceinline__ float b2f(bf16 v)  { return __bfloat162float(v); }
__device__ __forceinline__ bf16  f2b(float v) { return __float2bfloat16(v); }
__device__ __forceinline__ short sbf(float x) { bf16 b = __float2bfloat16(x); return *(short*)&b; }
__device__ __forceinline__ float ldf(const float* p) { return *p; }
__device__ __forceinline__ float ldf(const bf16*  p) { return b2f(*p); }
__device__ __forceinline__ void stf(float* p, float v) { *p = v; }
__device__ __forceinline__ void stf(bf16*  p, float v) { *p = f2b(v); }

// async global->LDS DMA, 16B per lane.
__device__ __forceinline__ void gl2lds(const bf16* g, short* l) {
    __builtin_amdgcn_global_load_lds(
        (const __attribute__((address_space(1))) void*)g,
        (__attribute__((address_space(3))) void*)l, 16, 0, 0);
}

// ---------------------------------------------------------------------------
// MFMA GEMM, 128x128 tile, BK=64 double-staged (round 10, kept: +15us).
// ---------------------------------------------------------------------------
template <int RELU>
__global__ __launch_bounds__(256)
void gemm_lds(const bf16* __restrict__ A, int lda, const bf16* __restrict__ Wt,
              const float* __restrict__ bias, bf16* __restrict__ C, int ldc,
              int N, int K)
{
    __shared__ __align__(16) short As[2][128 * 32];
    __shared__ __align__(16) short Bs[2][128 * 32];

    const int tid  = threadIdx.x;
    const int wave = tid >> 6, lane = tid & 63;
    const int wx = wave & 1, wy = wave >> 1;
    const int quad = lane >> 4, fn = lane & 15;
    const int bm = blockIdx.y * 128, bn = blockIdx.x * 128;
    const int l4 = lane >> 2, l8 = (lane & 3) * 8;

    const bf16* gA0 = A  + (size_t)(bm + wave * 16       + l4) * lda + l8;
    const bf16* gA1 = A  + (size_t)(bm + (wave + 4) * 16 + l4) * lda + l8;
    const bf16* gB0 = Wt + (size_t)(bn + wave * 16       + l4) * K   + l8;
    const bf16* gB1 = Wt + (size_t)(bn + (wave + 4) * 16 + l4) * K   + l8;
    const int cA0 = wave * 512, cA1 = (wave + 4) * 512;

    floatx4 acc[4][4] = {};

    for (int kk = 0; kk < K; kk += 64) {
        __syncthreads();
        gl2lds(gA0 + kk,      &As[0][cA0]);
        gl2lds(gA1 + kk,      &As[0][cA1]);
        gl2lds(gB0 + kk,      &Bs[0][cA0]);
        gl2lds(gB1 + kk,      &Bs[0][cA1]);
        gl2lds(gA0 + kk + 32, &As[1][cA0]);
        gl2lds(gA1 + kk + 32, &As[1][cA1]);
        gl2lds(gB0 + kk + 32, &Bs[1][cA0]);
        gl2lds(gB1 + kk + 32, &Bs[1][cA1]);
        __syncthreads();

        #pragma unroll
        for (int h = 0; h < 2; ++h) {
            short8 af[4], bfr[4];
            #pragma unroll
            for (int i = 0; i < 4; ++i) {
                af[i]  = *(const short8*)&As[h][(wy * 64 + i * 16 + fn) * 32 + quad * 8];
                bfr[i] = *(const short8*)&Bs[h][(wx * 64 + i * 16 + fn) * 32 + quad * 8];
            }
            #pragma unroll
            for (int i = 0; i < 4; ++i)
                #pragma unroll
                for (int j = 0; j < 4; ++j)
                    acc[i][j] = __builtin_amdgcn_mfma_f32_16x16x32_bf16(
                        af[i], bfr[j], acc[i][j], 0, 0, 0);
        }
    }

    #pragma unroll
    for (int j = 0; j < 4; ++j) {
        const int n = bn + wx * 64 + j * 16 + fn;
        const float bv = bias[n];
        #pragma unroll
        for (int i = 0; i < 4; ++i) {
            #pragma unroll
            for (int rg = 0; rg < 4; ++rg) {
                const int m = bm + wy * 64 + i * 16 + quad * 4 + rg;
                float v = acc[i][j][rg] + bv;
                if (RELU) v = fmaxf(v, 0.f);
                C[(size_t)m * ldc + n] = f2b(v);
            }
        }
    }
}

// ---------------------------------------------------------------------------
// MFMA GEMM, 64x64 tile, BK=64 double-staged (rounds 9+10, kept).
// ---------------------------------------------------------------------------
template <int RELU>
__global__ __launch_bounds__(256)
void gemm_lds64(const bf16* __restrict__ A, int lda, const bf16* __restrict__ Wt,
                const float* __restrict__ bias, bf16* __restrict__ C, int ldc,
                int N, int K)
{
    __shared__ __align__(16) short As[2][64 * 32];
    __shared__ __align__(16) short Bs[2][64 * 32];

    const int tid  = threadIdx.x;
    const int wave = tid >> 6, lane = tid & 63;
    const int wx = wave & 1, wy = wave >> 1;
    const int quad = lane >> 4, fn = lane & 15;
    const int bm = blockIdx.y * 64, bn = blockIdx.x * 64;
    const int l4 = lane >> 2, l8 = (lane & 3) * 8;

    const bf16* gA = A  + (size_t)(bm + wave * 16 + l4) * lda + l8;
    const bf16* gB = Wt + (size_t)(bn + wave * 16 + l4) * K   + l8;
    const int cw = wave * 512;

    floatx4 acc[2][2] = {};

    for (int kk = 0; kk < K; kk += 64) {
        __syncthreads();
        gl2lds(gA + kk,      &As[0][cw]);
        gl2lds(gB + kk,      &Bs[0][cw]);
        gl2lds(gA + kk + 32, &As[1][cw]);
        gl2lds(gB + kk + 32, &Bs[1][cw]);
        __syncthreads();

        #pragma unroll
        for (int h = 0; h < 2; ++h) {
            short8 af[2], bfr[2];
            #pragma unroll
            for (int i = 0; i < 2; ++i) {
                af[i]  = *(const short8*)&As[h][(wy * 32 + i * 16 + fn) * 32 + quad * 8];
                bfr[i] = *(const short8*)&Bs[h][(wx * 32 + i * 16 + fn) * 32 + quad * 8];
            }
            #pragma unroll
            for (int i = 0; i < 2; ++i)
                #pragma unroll
                for (int j = 0; j < 2; ++j)
                    acc[i][j] = __builtin_amdgcn_mfma_f32_16x16x32_bf16(
                        af[i], bfr[j], acc[i][j], 0, 0, 0);
        }
    }

    #pragma unroll
    for (int j = 0; j < 2; ++j) {
        const int n = bn + wx * 32 + j * 16 + fn;
        const float bv = bias[n];
        #pragma unroll
        for (int i = 0; i < 2; ++i) {
            #pragma unroll
            for (int rg = 0; rg < 4; ++rg) {
                const int m = bm + wy * 32 + i * 16 + quad * 4 + rg;
                float v = acc[i][j][rg] + bv;
                if (RELU) v = fmaxf(v, 0.f);
                C[(size_t)m * ldc + n] = f2b(v);
            }
        }
    }
}

// x (fp32) -> bf16, vectorized 8/thread.
__global__ __launch_bounds__(256)
void xcvt(const float* __restrict__ x, bf16* __restrict__ xb)
{
    const size_t i = ((size_t)blockIdx.x * 256 + threadIdx.x) * 8;
    const float4 a = *(const float4*)&x[i];
    const float4 b = *(const float4*)&x[i + 4];
    short8 v;
    v[0]=sbf(a.x); v[1]=sbf(a.y); v[2]=sbf(a.z); v[3]=sbf(a.w);
    v[4]=sbf(b.x); v[5]=sbf(b.y); v[6]=sbf(b.z); v[7]=sbf(b.w);
    *(short8*)&xb[i] = v;
}

// ---------------------------------------------------------------------------
// MFMA flash attention v9 = v6 body + CAUSAL FOLD (round 11).
//   Round-11 theory: v6's occupancy was 17% (1.4 blocks/CU) vs a 3-block LDS
//   ceiling because causal block work ranges 1..64 tiles — light blocks
//   drain early and CUs idle around heavy stragglers. Fold: grid.x halves
//   to 32; each block runs the v6 body TWICE sequentially —
//     pass 0: q0 = (63-bx)*64  (heavy, 64-bx tiles)
//     pass 1: q0 = bx*64       (light, bx+1 tiles)
//   => every block does exactly 65 tiles; 768 blocks = exactly 3/CU stay
//   resident for the whole makespan. Per-tile code identical to v6
//   (numerics unchanged); loop-top barrier already guards the cross-pass
//   Ks/Vt overwrite; barrier counts stay block-uniform.
// ---------------------------------------------------------------------------
__global__ __launch_bounds__(256)
void attn_v9(const bf16* __restrict__ QKV, bf16* __restrict__ Out)
{
    __shared__ __align__(16) short Ks[64 * 72];      // [key][d]
    __shared__ __align__(16) short Vt[64 * 72];      // [d][key]
    __shared__ __align__(16) float Ss[4][16 * 68];   // per-wave S [q][key] fp32
    __shared__ __align__(16) short Ps[4][16 * 72];   // per-wave P [q][key] bf16
    __shared__ float Al[4][16];                      // per-row alpha
    __shared__ float Ll[4][16];                      // per-row l

    const int tid  = threadIdx.x;
    const int wave = tid >> 6, lane = tid & 63;
    const int quad = lane >> 4, fn = lane & 15;
    const int bh = blockIdx.y;
    const int b = bh / NH, h = bh % NH;
    const int bx = blockIdx.x;

    const int orow = lane >> 2;              // 0..15 (owned q-row)
    const int okey = (lane & 3) * 16;        // 16-key slice base

    const short* QKVs = (const short*)QKV;   // bit view for LDS staging

    const int sk = tid >> 3, sc8 = (tid & 7) * 8;    // K staging: 32 rows/pass
    const int vd = tid & 63, vk4 = (tid >> 6) * 4;   // V staging: 4+4+4+4 keys
    const size_t gK = (size_t)(b * TS) * 2304 + 768  + h * 64 + (size_t)sk * 2304 + sc8;
    const size_t gV = (size_t)(b * TS) * 2304 + 1536 + h * 64 + vd;

    auto run = [&](const int q0) {
        const int nt = q0 / 64 + 1;              // 64-key tiles
        const int qwmin = q0 + wave * 16;

        const size_t rowQ = (size_t)(b * TS + q0 + wave * 16 + fn) * 2304 + h * 64;
        const short8 qa0 = *(const short8*)&QKV[rowQ + quad * 8];
        const short8 qa1 = *(const short8*)&QKV[rowQ + 32 + quad * 8];

        float mrow = NEG, lrow = 0.f;
        floatx4 o[4] = {};

        // prologue: load tile 0 into registers (bit copies — NaN fix preserved)
        short8 kr0 = *(const short8*)&QKVs[gK];
        short8 kr1 = *(const short8*)&QKVs[gK + (size_t)32 * 2304];
        short4b vr0, vr1, vr2, vr3;
        #pragma unroll
        for (int j = 0; j < 4; ++j) {
            vr0[j] = QKVs[gV + (size_t)(vk4 + j) * 2304];
            vr1[j] = QKVs[gV + (size_t)(16 + vk4 + j) * 2304];
            vr2[j] = QKVs[gV + (size_t)(32 + vk4 + j) * 2304];
            vr3[j] = QKVs[gV + (size_t)(48 + vk4 + j) * 2304];
        }

        for (int t = 0; t < nt; ++t) {
            const int kk0 = t * 64;
            __syncthreads();                 // reads of previous tile (or pass) done
            *(short8*)&Ks[sk * 72 + sc8]        = kr0;
            *(short8*)&Ks[(sk + 32) * 72 + sc8] = kr1;
            *(short4b*)&Vt[vd * 72 + vk4]       = vr0;
            *(short4b*)&Vt[vd * 72 + 16 + vk4]  = vr1;
            *(short4b*)&Vt[vd * 72 + 32 + vk4]  = vr2;
            *(short4b*)&Vt[vd * 72 + 48 + vk4]  = vr3;
            if (t + 1 < nt) {                // T14: issue next-tile loads early
                const size_t nk = (size_t)(kk0 + 64) * 2304;
                kr0 = *(const short8*)&QKVs[gK + nk];
                kr1 = *(const short8*)&QKVs[gK + nk + (size_t)32 * 2304];
                #pragma unroll
                for (int j = 0; j < 4; ++j) {
                    vr0[j] = QKVs[gV + nk + (size_t)(vk4 + j) * 2304];
                    vr1[j] = QKVs[gV + nk + (size_t)(16 + vk4 + j) * 2304];
                    vr2[j] = QKVs[gV + nk + (size_t)(32 + vk4 + j) * 2304];
                    vr3[j] = QKVs[gV + nk + (size_t)(48 + vk4 + j) * 2304];
                }
            }
            __syncthreads();                 // tile t staged

            if (kk0 > qwmin + 15) continue;  // fully masked for this wave

            // ---- S = Q K^T : 4 sub-tiles of 16 keys, 8 MFMA ----
            __builtin_amdgcn_s_setprio(1);
            floatx4 s[4] = {};
            #pragma unroll
            for (int ks = 0; ks < 4; ++ks) {
                const short8 ka = *(const short8*)&Ks[(ks * 16 + fn) * 72 + quad * 8];
                const short8 kb = *(const short8*)&Ks[(ks * 16 + fn) * 72 + 32 + quad * 8];
                s[ks] = __builtin_amdgcn_mfma_f32_16x16x32_bf16(qa0, ka, s[ks], 0, 0, 0);
                s[ks] = __builtin_amdgcn_mfma_f32_16x16x32_bf16(qa1, kb, s[ks], 0, 0, 0);
            }
            __builtin_amdgcn_s_setprio(0);

            // scale + mask, S -> wave-private LDS (no barrier needed)
            const int qg = q0 + wave * 16 + quad * 4;
            if (kk0 + 63 <= qwmin) {         // interior tile: mask statically true
                #pragma unroll
                for (int ks = 0; ks < 4; ++ks)
                    #pragma unroll
                    for (int rg = 0; rg < 4; ++rg)
                        Ss[wave][(quad * 4 + rg) * 68 + ks * 16 + fn] = s[ks][rg] * 0.125f;
            } else {
                #pragma unroll
                for (int ks = 0; ks < 4; ++ks)
                    #pragma unroll
                    for (int rg = 0; rg < 4; ++rg) {
                        const float v = (kk0 + ks * 16 + fn <= qg + rg)
                                            ? s[ks][rg] * 0.125f : NEG;
                        Ss[wave][(quad * 4 + rg) * 68 + ks * 16 + fn] = v;
                    }
            }

            // ---- LDS softmax (lane owns row lane>>2, 16-key slice) ----
            float sv[16];
            *(float4*)&sv[0]  = *(const float4*)&Ss[wave][orow * 68 + okey];
            *(float4*)&sv[4]  = *(const float4*)&Ss[wave][orow * 68 + okey + 4];
            *(float4*)&sv[8]  = *(const float4*)&Ss[wave][orow * 68 + okey + 8];
            *(float4*)&sv[12] = *(const float4*)&Ss[wave][orow * 68 + okey + 12];
            float mx = sv[0];
            #pragma unroll
            for (int j = 1; j < 16; ++j) mx = fmaxf(mx, sv[j]);
            mx = fmaxf(mx, __shfl_xor(mx, 1, 64));
            mx = fmaxf(mx, __shfl_xor(mx, 2, 64));
            const float mn2 = fmaxf(mrow, mx);
            float ps = 0.f;
            short8 pb0, pb1;
            #pragma unroll
            for (int j = 0; j < 8; ++j) {
                const float p = __expf(fminf(sv[j] - mn2, 0.f));
                ps += p;
                pb0[j] = sbf(p);
            }
            #pragma unroll
            for (int j = 0; j < 8; ++j) {
                const float p = __expf(fminf(sv[8 + j] - mn2, 0.f));
                ps += p;
                pb1[j] = sbf(p);
            }
            ps += __shfl_xor(ps, 1, 64);
            ps += __shfl_xor(ps, 2, 64);
            const float cr = __expf(fminf(mrow - mn2, 0.f));
            lrow = lrow * cr + ps;
            mrow = mn2;
            *(short8*)&Ps[wave][orow * 72 + okey]     = pb0;
            *(short8*)&Ps[wave][orow * 72 + okey + 8] = pb1;
            if ((lane & 3) == 0) { Al[wave][orow] = cr; Ll[wave][orow] = lrow; }

            // ---- rescale accumulator + PV MFMA (wave-private, no barrier) ----
            float al[4];
            #pragma unroll
            for (int rg = 0; rg < 4; ++rg) al[rg] = Al[wave][quad * 4 + rg];
            #pragma unroll
            for (int cb = 0; cb < 4; ++cb)
                #pragma unroll
                for (int rg = 0; rg < 4; ++rg) o[cb][rg] *= al[rg];
            const short8 pf0 = *(const short8*)&Ps[wave][fn * 72 + quad * 8];
            const short8 pf1 = *(const short8*)&Ps[wave][fn * 72 + 32 + quad * 8];
            __builtin_amdgcn_s_setprio(1);
            #pragma unroll
            for (int cb = 0; cb < 4; ++cb) {
                const short8 vfa = *(const short8*)&Vt[(cb * 16 + fn) * 72 + quad * 8];
                o[cb] = __builtin_amdgcn_mfma_f32_16x16x32_bf16(pf0, vfa, o[cb], 0, 0, 0);
            }
            #pragma unroll
            for (int cb = 0; cb < 4; ++cb) {
                const short8 vfb = *(const short8*)&Vt[(cb * 16 + fn) * 72 + 32 + quad * 8];
                o[cb] = __builtin_amdgcn_mfma_f32_16x16x32_bf16(pf1, vfb, o[cb], 0, 0, 0);
            }
            __builtin_amdgcn_s_setprio(0);
        }

        float li[4];
        #pragma unroll
        for (int rg = 0; rg < 4; ++rg)
            li[rg] = 1.f / fmaxf(Ll[wave][quad * 4 + rg], 1e-20f);
        #pragma unroll
        for (int cb = 0; cb < 4; ++cb)
            #pragma unroll
            for (int rg = 0; rg < 4; ++rg) {
                const size_t row = (size_t)(b * TS + q0 + wave * 16 + quad * 4 + rg);
                Out[row * DM + h * 64 + cb * 16 + fn] = f2b(o[cb][rg] * li[rg]);
            }
    };

    run((TS / 64 - 1 - bx) * 64);   // heavy pass: 64-bx tiles
    run(bx * 64);                   // light pass: bx+1 tiles  => 65 total
}

// ---------------------------------------------------------------------------
__global__ __launch_bounds__(256)
void transW(const float* __restrict__ W, bf16* __restrict__ Wt, int K, int N)
{
    __shared__ float t[32][33];
    const int k0 = blockIdx.x * 32, n0 = blockIdx.y * 32;
    const int tx = threadIdx.x, ty = threadIdx.y;
    #pragma unroll
    for (int i = 0; i < 4; ++i)
        t[ty + i * 8][tx] = W[(size_t)(k0 + ty + i * 8) * N + n0 + tx];
    __syncthreads();
    #pragma unroll
    for (int i = 0; i < 4; ++i)
        Wt[(size_t)(n0 + ty + i * 8) * K + k0 + tx] = f2b(t[tx][ty + i * 8]);
}

__global__ __launch_bounds__(256)
void pack_bias(const float* __restrict__ bq, const float* __restrict__ bk,
               const float* __restrict__ bv, float* __restrict__ out)
{
    const int i = blockIdx.x * 256 + threadIdx.x;
    if (i < 3 * DM)
        out[i] = (i < DM) ? bq[i] : (i < 2 * DM) ? bk[i - DM] : bv[i - 2 * DM];
}

template <typename T1, typename T2, typename TOUT>
__global__ __launch_bounds__(256)
void add_ln(const T1* __restrict__ a, const T2* __restrict__ r, int ldr,
            const float* __restrict__ gamma, const float* __restrict__ beta,
            TOUT* __restrict__ out)
{
    const int row = blockIdx.x;
    const size_t offa = (size_t)row * DM;
    const size_t offr = (size_t)row * ldr;
    const int tid = threadIdx.x;

    float v[3];
    float s = 0.f, s2 = 0.f;
    #pragma unroll
    for (int j = 0; j < 3; ++j) {
        const int i = tid + j * 256;
        const float t = ldf(a + offa + i) + ldf(r + offr + i);
        v[j] = t; s += t; s2 += t * t;
    }
    __shared__ float red[256], red2[256];
    red[tid] = s; red2[tid] = s2;
    __syncthreads();
    #pragma unroll
    for (int st = 128; st > 0; st >>= 1) {
        if (tid < st) { red[tid] += red[tid + st]; red2[tid] += red2[tid + st]; }
        __syncthreads();
    }
    const float mu   = red[0] * (1.f / DM);
    const float var  = red2[0] * (1.f / DM) - mu * mu;
    const float rstd = rsqrtf(var + EPS);
    #pragma unroll
    for (int j = 0; j < 3; ++j) {
        const int i = tid + j * 256;
        stf(out + offa + i, (v[j] - mu) * rstd * gamma[i] + beta[i]);
    }
}

// ---------------------------------------------------------------------------
extern "C" void kernel_launch(void* const* d_in, const int* in_sizes, int n_in,
                              void* d_out, int out_size, void* d_ws, size_t ws_size,
                              hipStream_t stream)
{
    (void)in_sizes; (void)n_in; (void)out_size; (void)ws_size;

    const float* x   = (const float*)d_in[0];
    const float* wq  = (const float*)d_in[1];  const float* bq  = (const float*)d_in[2];
    const float* wk  = (const float*)d_in[3];  const float* bk  = (const float*)d_in[4];
    const float* wv  = (const float*)d_in[5];  const float* bv  = (const float*)d_in[6];
    const float* wo  = (const float*)d_in[7];  const float* bo  = (const float*)d_in[8];
    const float* w1  = (const float*)d_in[9];  const float* b1  = (const float*)d_in[10];
    const float* w2  = (const float*)d_in[11]; const float* b2  = (const float*)d_in[12];
    const float* g1  = (const float*)d_in[13]; const float* be1 = (const float*)d_in[14];
    const float* g2  = (const float*)d_in[15]; const float* be2 = (const float*)d_in[16];

    // ws layout (bf16 elems), ~59.8 MB (proven round 6):
    //   QKVb [8192][2304] = 3S | Hb = S | wbuf = 2*DFF*DM | bqkv fp32[2304]
    const size_t S = (size_t)MTOK * DM;
    bf16* QKVb = (bf16*)d_ws;
    bf16* Hb   = QKVb + 3 * S;
    bf16* wbuf = Hb + S;
    float* bqkv = (float*)(wbuf + (size_t)2 * DFF * DM);
    bf16* F1 = QKVb;              // FFN hidden chunk [4096][3072]
    bf16* Yb = QKVb + 2 * S;      // FFN out
    bf16* Pb = QKVb + DM;         // O-proj out -> K-band (dead), ld 2304
    bf16* Ao = Hb;                // attention out (dense; Hb free until LN1)
    bf16* xb = Hb;                // x as bf16 (dead after QKV proj; Hb free)

    const dim3 tblk(32, 8);
    const dim3 blk(256);

    // x -> bf16 (enables global_load_lds staging in the QKV GEMM)
    xcvt<<<dim3(3072), blk, 0, stream>>>(x, xb);

    // QKV projection (well-gridded: 1152 blocks at 128^2)
    transW<<<dim3(24, 24), tblk, 0, stream>>>(wq, wbuf,                    DM, DM);
    transW<<<dim3(24, 24), tblk, 0, stream>>>(wk, wbuf + (size_t)DM * DM,  DM, DM);
    transW<<<dim3(24, 24), tblk, 0, stream>>>(wv, wbuf + (size_t)2*DM*DM,  DM, DM);
    pack_bias<<<dim3(9), blk, 0, stream>>>(bq, bk, bv, bqkv);
    gemm_lds<0><<<dim3(18, 64), blk, 0, stream>>>(
        xb, DM, wbuf, bqkv, QKVb, 3 * DM, 3 * DM, DM);

    // MFMA flash attention -> Ao (dense 768; overwrites dead xb)
    // Causal fold: 32x24 = 768 blocks = exactly 3/CU, all equal work.
    attn_v9<<<dim3(32, NB * NH), blk, 0, stream>>>(QKVb, Ao);

    // O-projection: 64^2 tiles -> (12,128) = 1536 blocks
    transW<<<dim3(24, 24), tblk, 0, stream>>>(wo, wbuf, DM, DM);
    gemm_lds64<0><<<dim3(12, 128), blk, 0, stream>>>(
        Ao, DM, wbuf, bo, Pb, 3 * DM, DM, DM);
    add_ln<float, bf16, bf16><<<dim3(MTOK), blk, 0, stream>>>(
        x, Pb, 3 * DM, g1, be1, Hb);

    // FFN (chunked over M; F1/Yb live in the dead QKVb region)
    transW<<<dim3(24, 96), tblk, 0, stream>>>(w1, wbuf, DM, DFF);
    bf16* w2t = wbuf + (size_t)DFF * DM;
    transW<<<dim3(96, 24), tblk, 0, stream>>>(w2, w2t, DFF, DM);
    for (int m0 = 0; m0 < MTOK; m0 += 4096) {
        gemm_lds<1><<<dim3(24, 32), blk, 0, stream>>>(
            Hb + (size_t)m0 * DM, DM, wbuf, b1, F1, DFF, DFF, DM);
        // FFN2: 64^2 tiles -> (12,64) = 768 blocks = 3/CU
        gemm_lds64<0><<<dim3(12, 64), blk, 0, stream>>>(
            F1, DFF, w2t, b2, Yb + (size_t)m0 * DM, DM, DM, DFF);
    }

    add_ln<bf16, bf16, float><<<dim3(MTOK), blk, 0, stream>>>(
        Hb, Yb, DM, g2, be2, (float*)d_out);
}